// Round 9
// baseline (188.109 us; speedup 1.0000x reference)
//
#include <hip/hip_runtime.h>
#include <math.h>

// ---------------------------------------------------------------------------
// Performer encoder layer, MI355X round-9: 256x256 8-wave interleaved-phase
// GEMM (gemm8p: T3 phase-interleave + T5 setprio, 128KB dbuf LDS) for
// FFN1 + QKV; rest as round-8.
// N=8192, D=512, H=8, DH=64, NF=266 (padded to NFP=320 = 5*64).
// Workspace layout: unchanged from round-8.
// ---------------------------------------------------------------------------

typedef __attribute__((ext_vector_type(8))) short bf16x8;
typedef __attribute__((ext_vector_type(4))) float f32x4;

#define N_SEQ 8192
#define DMODEL 512
#define DQKV 1536
#define NHEAD 8
#define DHEAD 64
#define NF 266
#define NFP 320
#define PEPS 1e-4f
#define LNEPS 1e-5f
#define RATIO 0.06131393694f

__device__ __forceinline__ unsigned short f2bf(float f) {
  unsigned u = __float_as_uint(f);
  u += 0x7FFFu + ((u >> 16) & 1u);
  return (unsigned short)(u >> 16);
}
__device__ __forceinline__ float bf2f(unsigned short b) {
  return __uint_as_float(((unsigned)b) << 16);
}
__device__ __forceinline__ unsigned enc_f32(float f) {
  unsigned i = __float_as_uint(f);
  return (i & 0x80000000u) ? ~i : (i | 0x80000000u);
}
__device__ __forceinline__ float dec_f32(unsigned u) {
  return (u & 0x80000000u) ? __uint_as_float(u & 0x7FFFFFFFu) : __uint_as_float(~u);
}

__device__ __forceinline__ void g2l16(const void* g, void* l) {
  __builtin_amdgcn_global_load_lds(
      (const __attribute__((address_space(1))) void*)g,
      (__attribute__((address_space(3))) void*)l, 16, 0, 0);
}

template <int N>
__device__ __forceinline__ void wait_vmcnt() {
  if constexpr (N == 0) asm volatile("s_waitcnt vmcnt(0)" ::: "memory");
  else if constexpr (N == 8) asm volatile("s_waitcnt vmcnt(8)" ::: "memory");
}
__device__ __forceinline__ void wait_lgkm0() {
  asm volatile("s_waitcnt lgkmcnt(0)" ::: "memory");
}

// -------------------- fused prep --------------------

__global__ __launch_bounds__(256) void prep_kernel(
    const float* __restrict__ wq, const float* __restrict__ wk,
    const float* __restrict__ wv, const float* __restrict__ wo,
    const float* __restrict__ w1, const float* __restrict__ w2,
    const float* __restrict__ proj,
    unsigned short* __restrict__ wtqkv, unsigned short* __restrict__ wot,
    unsigned short* __restrict__ w1t, unsigned short* __restrict__ w2t,
    unsigned short* __restrict__ pb, unsigned* __restrict__ mk) {
  int bid = blockIdx.x;
  if (bid < 3072) {
    const float* src; unsigned short* dst; int R, C, base;
    if (bid < 256)       { src = wq; dst = wtqkv;          R = 512;  C = 512;  base = 0; }
    else if (bid < 512)  { src = wk; dst = wtqkv + 262144; R = 512;  C = 512;  base = 256; }
    else if (bid < 768)  { src = wv; dst = wtqkv + 524288; R = 512;  C = 512;  base = 512; }
    else if (bid < 1024) { src = wo; dst = wot;            R = 512;  C = 512;  base = 768; }
    else if (bid < 2048) { src = w1; dst = w1t;            R = 512;  C = 2048; base = 1024; }
    else                 { src = w2; dst = w2t;            R = 2048; C = 512;  base = 2048; }
    int lb = bid - base;
    int nbx = C / 32;
    int c0 = (lb % nbx) * 32, r0 = (lb / nbx) * 32;
    __shared__ float tile[32][33];
    int tx = threadIdx.x & 31, ty = threadIdx.x >> 5;
    #pragma unroll
    for (int i = ty; i < 32; i += 8)
      tile[i][tx] = src[(long)(r0 + i) * C + c0 + tx];
    __syncthreads();
    #pragma unroll
    for (int i = ty; i < 32; i += 8)
      dst[(long)(c0 + i) * R + r0 + tx] = f2bf(tile[tx][i]);
  } else if (bid < 3152) {
    int id = (bid - 3072) * 256 + threadIdx.x;  // < 320*64
    int j = id >> 6;
    pb[id] = (j < NF) ? f2bf(proj[(long)j * 64 + (id & 63)] * 0.35355339059327373f)
                      : (unsigned short)0;
  } else {
    if (threadIdx.x < NHEAD) mk[threadIdx.x] = 0x007FFFFFu;  // enc(-inf)
  }
}

// -------------------- layernorm --------------------

__global__ __launch_bounds__(256) void ln_kernel(const float* __restrict__ x,
                                                 const float* __restrict__ g,
                                                 const float* __restrict__ b,
                                                 unsigned short* __restrict__ out) {
  __shared__ float sred[4];
  int row = blockIdx.x, t = threadIdx.x;
  float2 v = ((const float2*)(x + (long)row * DMODEL))[t];
  float s = v.x + v.y;
  #pragma unroll
  for (int m = 32; m >= 1; m >>= 1) s += __shfl_xor(s, m);
  if ((t & 63) == 0) sred[t >> 6] = s;
  __syncthreads();
  float mu = (sred[0] + sred[1] + sred[2] + sred[3]) * (1.0f / DMODEL);
  __syncthreads();
  float d0 = v.x - mu, d1 = v.y - mu;
  float q = d0 * d0 + d1 * d1;
  #pragma unroll
  for (int m = 32; m >= 1; m >>= 1) q += __shfl_xor(q, m);
  if ((t & 63) == 0) sred[t >> 6] = q;
  __syncthreads();
  float var = (sred[0] + sred[1] + sred[2] + sred[3]) * (1.0f / DMODEL);
  float inv = rsqrtf(var + LNEPS);
  int c = t * 2;
  unsigned short o0 = f2bf(d0 * inv * g[c] + b[c]);
  unsigned short o1 = f2bf(d1 * inv * g[c + 1] + b[c + 1]);
  ((unsigned*)(out + (long)row * DMODEL))[t] = ((unsigned)o1 << 16) | o0;
}

enum { EPI_BF16 = 0, EPI_BIAS_RES_F32 = 2, EPI_BIAS_GELU = 3, EPI_QKV = 4 };

// -------------------- 256x256 8-wave interleaved-phase GEMM ------------------
// 512 threads = 8 waves (2M x 4N), WM=128, WN=64, BK=64, 128KB dbuf LDS.
// Per K-tile: 2 phases, each = {issue 4 stage rounds for t+1 | ds_read frags |
// setprio(1) 32 MFMA setprio(0)}; tile end: lgkm0+bar, vmcnt(0)+bar.

template <int EPI>
__global__ __launch_bounds__(512, 1) void gemm8p_kernel(
    const unsigned short* __restrict__ A, int lda,
    const unsigned short* __restrict__ Bt, int ldb,
    void* __restrict__ Cv, int ldc,
    int K,
    const float* __restrict__ bias,
    unsigned short* __restrict__ vt) {
  constexpr int MR = 8, NR = 4;
  const int tid = threadIdx.x;
  const int wave = tid >> 6, lane = tid & 63;
  const int lr = lane & 15, lg = lane >> 4;
  const int wr = wave >> 2, wc = wave & 3;  // 2M x 4N
  const int m0 = blockIdx.x * 256, n0 = blockIdx.y * 256;

  __shared__ uint4 a_s[2][2048];
  __shared__ uint4 b_s[2][2048];

  const unsigned short* asrc[4];
  const unsigned short* bsrc[4];
  #pragma unroll
  for (int e = 0; e < 4; ++e) {
    int chunk = e * 512 + tid;
    int r = chunk >> 3, c = chunk & 7;
    asrc[e] = A + (long)(m0 + r) * lda + (c ^ (r & 7)) * 8;
    bsrc[e] = Bt + (long)(n0 + r) * ldb + (c ^ (r & 7)) * 8;
  }
  const int wbase = tid & 448;

  f32x4 acc[MR][NR] = {};

  auto stage_a = [&](int buf, int t) {
    #pragma unroll
    for (int e = 0; e < 4; ++e)
      g2l16(asrc[e] + t * 64, &a_s[buf][e * 512 + wbase]);
  };
  auto stage_b = [&](int buf, int t) {
    #pragma unroll
    for (int e = 0; e < 4; ++e)
      g2l16(bsrc[e] + t * 64, &b_s[buf][e * 512 + wbase]);
  };
  auto compute_ks = [&](int buf, int ks) {
    bf16x8 af[MR], bv[NR];
    #pragma unroll
    for (int i = 0; i < MR; ++i) {
      int r = wr * 128 + i * 16 + lr;
      af[i] = *(const bf16x8*)&a_s[buf][r * 8 + ((ks * 4 + lg) ^ (r & 7))];
    }
    #pragma unroll
    for (int j = 0; j < NR; ++j) {
      int r = wc * 64 + j * 16 + lr;
      bv[j] = *(const bf16x8*)&b_s[buf][r * 8 + ((ks * 4 + lg) ^ (r & 7))];
    }
    __builtin_amdgcn_s_setprio(1);
    #pragma unroll
    for (int i = 0; i < MR; ++i)
      #pragma unroll
      for (int j = 0; j < NR; ++j)
        acc[i][j] = __builtin_amdgcn_mfma_f32_16x16x32_bf16(af[i], bv[j], acc[i][j], 0, 0, 0);
    __builtin_amdgcn_s_setprio(0);
  };

  const int NT = K >> 6;
  stage_a(0, 0);
  stage_b(0, 0);
  wait_vmcnt<0>();
  __builtin_amdgcn_s_barrier();

  for (int t = 0; t < NT; ++t) {
    const int cur = t & 1;
    const bool more = (t + 1 < NT);
    if (more) stage_a(cur ^ 1, t + 1);  // phase 0: issue A of t+1
    compute_ks(cur, 0);
    if (more) stage_b(cur ^ 1, t + 1);  // phase 1: issue B of t+1
    compute_ks(cur, 1);
    if (more) {
      wait_lgkm0();
      __builtin_amdgcn_sched_barrier(0);
      __builtin_amdgcn_s_barrier();     // all waves done reading buf cur
      wait_vmcnt<0>();                  // t+1 landed
      __builtin_amdgcn_s_barrier();
    }
  }

  #pragma unroll
  for (int i = 0; i < MR; ++i) {
    #pragma unroll
    for (int j = 0; j < NR; ++j) {
      int gn = n0 + wc * 64 + j * 16 + lr;
      int gm0 = m0 + wr * 128 + i * 16 + lg * 4;
      if (EPI == EPI_QKV && gn >= 1024) {
        int d = gn - 1024;
        uint2 u;
        u.x = (unsigned)f2bf(acc[i][j][0]) | ((unsigned)f2bf(acc[i][j][1]) << 16);
        u.y = (unsigned)f2bf(acc[i][j][2]) | ((unsigned)f2bf(acc[i][j][3]) << 16);
        *(uint2*)(vt + (long)d * N_SEQ + gm0) = u;
        continue;
      }
      #pragma unroll
      for (int rg = 0; rg < 4; ++rg) {
        int gm = gm0 + rg;
        float v = acc[i][j][rg];
        if (EPI == EPI_BF16 || EPI == EPI_QKV) {
          ((unsigned short*)Cv)[(long)gm * ldc + gn] = f2bf(v);
        } else if (EPI == EPI_BIAS_GELU) {
          v += bias[gn];
          float t3 = 0.7978845608028654f * (v + 0.044715f * v * v * v);
          v = v / (1.0f + __expf(-2.0f * t3));  // 0.5v(1+tanh(t3))
          ((unsigned short*)Cv)[(long)gm * ldc + gn] = f2bf(v);
        }
      }
    }
  }
}

// -------- counted-vmcnt double-buffered 128-tile 4-wave GEMM (WO/FFN2) -------

template <int BM, int BN, int WM, int WN, int EPI>
__global__ __launch_bounds__(256) void gemm_kernel(
    const unsigned short* __restrict__ A, int lda,
    const unsigned short* __restrict__ Bt, int ldb,
    void* __restrict__ Cv, int ldc,
    int K,
    const float* __restrict__ bias,
    const float* __restrict__ res, int ldr) {
  static_assert((BM / WM) * (BN / WN) == 4, "need 4 waves");
  constexpr int MR = WM / 16, NR = WN / 16;
  constexpr int WNN = BN / WN;
  constexpr int AIT = BM * 8 / 256;
  constexpr int BIT = BN * 8 / 256;
  const int tid = threadIdx.x;
  const int wave = tid >> 6, lane = tid & 63;
  const int lr = lane & 15, lg = lane >> 4;
  const int wr = wave / WNN, wc = wave % WNN;
  const int m0 = blockIdx.x * BM, n0 = blockIdx.y * BN;

  __shared__ uint4 a_s[2][BM * 8];
  __shared__ uint4 b_s[2][BN * 8];

  const unsigned short* asrc[AIT];
  #pragma unroll
  for (int e = 0; e < AIT; ++e) {
    int chunk = e * 256 + tid;
    int r = chunk >> 3, c = chunk & 7;
    asrc[e] = A + (long)(m0 + r) * lda + (c ^ (r & 7)) * 8;
  }
  const unsigned short* bsrc[BIT];
  #pragma unroll
  for (int e = 0; e < BIT; ++e) {
    int chunk = e * 256 + tid;
    int r = chunk >> 3, c = chunk & 7;
    bsrc[e] = Bt + (long)(n0 + r) * ldb + (c ^ (r & 7)) * 8;
  }
  const int wbase = tid & 192;

  f32x4 acc[MR][NR] = {};

  auto stage = [&](int buf, int t) {
    #pragma unroll
    for (int e = 0; e < AIT; ++e)
      g2l16(asrc[e] + t * 64, &a_s[buf][e * 256 + wbase]);
    #pragma unroll
    for (int e = 0; e < BIT; ++e)
      g2l16(bsrc[e] + t * 64, &b_s[buf][e * 256 + wbase]);
  };
  auto compute = [&](int buf) {
    #pragma unroll
    for (int ks = 0; ks < 2; ++ks) {
      bf16x8 af[MR], bv[NR];
      #pragma unroll
      for (int i = 0; i < MR; ++i) {
        int r = wr * WM + i * 16 + lr;
        af[i] = *(const bf16x8*)&a_s[buf][r * 8 + ((ks * 4 + lg) ^ (r & 7))];
      }
      #pragma unroll
      for (int j = 0; j < NR; ++j) {
        int r = wc * WN + j * 16 + lr;
        bv[j] = *(const bf16x8*)&b_s[buf][r * 8 + ((ks * 4 + lg) ^ (r & 7))];
      }
      #pragma unroll
      for (int i = 0; i < MR; ++i)
        #pragma unroll
        for (int j = 0; j < NR; ++j)
          acc[i][j] = __builtin_amdgcn_mfma_f32_16x16x32_bf16(af[i], bv[j], acc[i][j], 0, 0, 0);
    }
  };

  const int NT = K >> 6;
  stage(0, 0);
  stage(1, 1);
  wait_vmcnt<8>();
  __builtin_amdgcn_s_barrier();

  int cur = 0;
  for (int t = 0; t < NT; ++t) {
    compute(cur);
    if (t + 1 < NT) {
      wait_lgkm0();
      __builtin_amdgcn_s_barrier();
      if (t + 2 < NT) {
        stage(cur, t + 2);
        wait_vmcnt<8>();
      } else {
        wait_vmcnt<0>();
      }
      __builtin_amdgcn_s_barrier();
    }
    cur ^= 1;
  }

  #pragma unroll
  for (int i = 0; i < MR; ++i) {
    #pragma unroll
    for (int j = 0; j < NR; ++j) {
      int gn = n0 + wc * WN + j * 16 + lr;
      #pragma unroll
      for (int rg = 0; rg < 4; ++rg) {
        int gm = m0 + wr * WM + i * 16 + lg * 4 + rg;
        float v = acc[i][j][rg];
        if (EPI == EPI_BF16) {
          ((unsigned short*)Cv)[(long)gm * ldc + gn] = f2bf(v);
        } else if (EPI == EPI_BIAS_RES_F32) {
          v += bias[gn] + res[(long)gm * ldr + gn];
          ((float*)Cv)[(long)gm * ldc + gn] = v;
        } else if (EPI == EPI_BIAS_GELU) {
          v += bias[gn];
          float t3 = 0.7978845608028654f * (v + 0.044715f * v * v * v);
          v = v / (1.0f + __expf(-2.0f * t3));
          ((unsigned short*)Cv)[(long)gm * ldc + gn] = f2bf(v);
        }
      }
    }
  }
}

// -------------------- kmax: global max of dd(k) per head --------------------

__global__ __launch_bounds__(256) void kmax_kernel(
    const unsigned short* __restrict__ Kp,
    const unsigned short* __restrict__ pb,
    unsigned* __restrict__ mk) {
  const int tid = threadIdx.x;
  const int wave = tid >> 6, lane = tid & 63;
  const int lr = lane & 15, lg = lane >> 4;
  const int h = blockIdx.z;
  const int m0 = blockIdx.x * 64;

  __shared__ uint4 a_s4[512];
  __shared__ uint4 b_s4[2560];
  __shared__ float sred[4];

  const unsigned short* Aq = Kp + (long)m0 * DQKV + h * DHEAD;
  const int wbase = tid & 192;

  #pragma unroll
  for (int e = 0; e < 2; ++e) {
    int chunk = e * 256 + tid;
    int r = chunk >> 3, c = chunk & 7;
    g2l16(Aq + (long)r * DQKV + (c ^ (r & 7)) * 8, a_s4 + e * 256 + wbase);
  }
  #pragma unroll
  for (int e = 0; e < 10; ++e) {
    int chunk = e * 256 + tid;
    int r = chunk >> 3, c = chunk & 7;
    g2l16(pb + (long)r * DHEAD + (c ^ (r & 7)) * 8, b_s4 + e * 256 + wbase);
  }
  __syncthreads();

  f32x4 acc[17] = {};
  #pragma unroll
  for (int ks = 0; ks < 2; ++ks) {
    int rA = wave * 16 + lr;
    bf16x8 af = *(const bf16x8*)&a_s4[rA * 8 + ((ks * 4 + lg) ^ (rA & 7))];
    #pragma unroll
    for (int j = 0; j < 17; ++j) {
      int rB = j * 16 + lr;
      bf16x8 bv = *(const bf16x8*)&b_s4[rB * 8 + ((ks * 4 + lg) ^ (rB & 7))];
      acc[j] = __builtin_amdgcn_mfma_f32_16x16x32_bf16(af, bv, acc[j], 0, 0, 0);
    }
  }

  float m = -3.0e38f;
  #pragma unroll
  for (int j = 0; j < 17; ++j) {
    bool valid = (j < 16) || (lr < 10);
    if (valid) {
      #pragma unroll
      for (int rg = 0; rg < 4; ++rg) m = fmaxf(m, acc[j][rg]);
    }
  }
  #pragma unroll
  for (int s = 1; s < 64; s <<= 1) m = fmaxf(m, __shfl_xor(m, s));
  if (lane == 0) sred[wave] = m;
  __syncthreads();
  if (tid == 0) {
    float mm = fmaxf(fmaxf(sred[0], sred[1]), fmaxf(sred[2], sred[3]));
    atomicMax(&mk[h], enc_f32(mm));
  }
}

// -------------------- ctx_fused: phi(k) + kp^T v + colsums -------------------

__global__ __launch_bounds__(256) void ctx_fused_kernel(
    const unsigned short* __restrict__ Kp,
    const unsigned short* __restrict__ pb,
    const unsigned short* __restrict__ vT,
    const unsigned* __restrict__ mk,
    float* __restrict__ part,
    float* __restrict__ kspart) {
  const int tid = threadIdx.x;
  const int wave = tid >> 6, lane = tid & 63;
  const int lr = lane & 15, lg = lane >> 4;
  const int kc = blockIdx.x, h = blockIdx.y;
  const int wbase = tid & 192;

  __shared__ uint4 smem[7168];
  uint4* pbs = smem;
  auto kbuf = [&](int b) { return smem + 2560 + b * 512; };
  auto vbuf = [&](int b) { return smem + 3584 + b * 512; };
  uint4* Pt = smem + 4608;

  #pragma unroll
  for (int e = 0; e < 10; ++e) {
    int chunk = e * 256 + tid;
    int r = chunk >> 3, c = chunk & 7;
    g2l16(pb + (long)r * DHEAD + (c ^ (r & 7)) * 8, pbs + e * 256 + wbase);
  }

  auto stage_kv = [&](int b, int sub) {
    int n0 = kc * 256 + sub * 64;
    #pragma unroll
    for (int e = 0; e < 2; ++e) {
      int chunk = e * 256 + tid;
      int r = chunk >> 3, c = chunk & 7;
      g2l16(Kp + (long)(n0 + r) * DQKV + h * DHEAD + (c ^ (r & 7)) * 8,
            kbuf(b) + e * 256 + wbase);
      g2l16(vT + ((long)h * DHEAD + r) * N_SEQ + n0 + (c ^ (r & 7)) * 8,
            vbuf(b) + e * 256 + wbase);
    }
  };

  const float mh = dec_f32(mk[h]);
  f32x4 acc2[2][10] = {};
  float colacc[20];
  #pragma unroll
  for (int j = 0; j < 20; ++j) colacc[j] = 0.f;

  const int wr = wave >> 1, wc = wave & 1;

  stage_kv(0, 0);
  for (int sub = 0; sub < 4; ++sub) {
    const int cur = sub & 1;
    __syncthreads();
    if (sub + 1 < 4) stage_kv(cur ^ 1, sub + 1);

    f32x4 acc[20] = {};
    float qs = 0.f;
    #pragma unroll
    for (int ks = 0; ks < 2; ++ks) {
      int rA = wave * 16 + lr;
      bf16x8 af = *(const bf16x8*)&kbuf(cur)[rA * 8 + ((ks * 4 + lg) ^ (rA & 7))];
      #pragma unroll
      for (int i = 0; i < 8; ++i) {
        float f = bf2f((unsigned short)af[i]);
        qs += f * f;
      }
      #pragma unroll
      for (int j = 0; j < 20; ++j) {
        int rB = j * 16 + lr;
        bf16x8 bv = *(const bf16x8*)&pbs[rB * 8 + ((ks * 4 + lg) ^ (rB & 7))];
        acc[j] = __builtin_amdgcn_mfma_f32_16x16x32_bf16(af, bv, acc[j], 0, 0, 0);
      }
    }
    qs += __shfl_xor(qs, 16);
    qs += __shfl_xor(qs, 32);
    float dg[4];
    #pragma unroll
    for (int rg = 0; rg < 4; ++rg) dg[rg] = 0.0625f * __shfl(qs, lg * 4 + rg);

    __syncthreads();

    unsigned short* Ptu = (unsigned short*)Pt;
    const int nrow = wave * 16 + lg * 4;
    #pragma unroll
    for (int j = 0; j < 20; ++j) {
      int colj = j * 16 + lr;
      #pragma unroll
      for (int rg = 0; rg < 4; ++rg) {
        float v = 0.f;
        if (colj < NF) v = RATIO * (__expf(acc[j][rg] - dg[rg] - mh) + PEPS);
        colacc[j] += v;
        int nr = nrow + rg;
        int idx = ((colj * 8 + ((nr >> 3) ^ (colj & 7))) << 3) + (nr & 7);
        Ptu[idx] = f2bf(v);
      }
    }
    __syncthreads();

    #pragma unroll
    for (int ks = 0; ks < 2; ++ks) {
      bf16x8 af[2], bv[10];
      #pragma unroll
      for (int i = 0; i < 2; ++i) {
        int r = wr * 32 + i * 16 + lr;
        af[i] = *(const bf16x8*)&vbuf(cur)[r * 8 + ((ks * 4 + lg) ^ (r & 7))];
      }
      #pragma unroll
      for (int j = 0; j < 10; ++j) {
        int r = wc * 160 + j * 16 + lr;
        bv[j] = *(const bf16x8*)&Pt[r * 8 + ((ks * 4 + lg) ^ (r & 7))];
      }
      #pragma unroll
      for (int i = 0; i < 2; ++i)
        #pragma unroll
        for (int j = 0; j < 10; ++j)
          acc2[i][j] = __builtin_amdgcn_mfma_f32_16x16x32_bf16(af[i], bv[j], acc2[i][j], 0, 0, 0);
    }
  }

  float* pbase = part + ((long)(h * 32 + kc)) * 64 * NFP;
  #pragma unroll
  for (int i = 0; i < 2; ++i) {
    #pragma unroll
    for (int j = 0; j < 10; ++j) {
      int gn = wc * 160 + j * 16 + lr;
      #pragma unroll
      for (int rg = 0; rg < 4; ++rg) {
        int gm = wr * 32 + i * 16 + lg * 4 + rg;
        pbase[(long)gm * NFP + gn] = acc2[i][j][rg];
      }
    }
  }

  __syncthreads();
  float* kls = (float*)Pt;
  #pragma unroll
  for (int j = 0; j < 20; ++j) {
    float cs = colacc[j];
    cs += __shfl_xor(cs, 16);
    cs += __shfl_xor(cs, 32);
    if (lg == 0) kls[wave * NFP + j * 16 + lr] = cs;
  }
  __syncthreads();
  for (int c0 = tid; c0 < NFP; c0 += 256) {
    kspart[((long)(h * 32 + kc)) * NFP + c0] =
        kls[c0] + kls[NFP + c0] + kls[2 * NFP + c0] + kls[3 * NFP + c0];
  }
}

// -------------------- ctxpad build --------------------

__global__ void ctx_reduce_kernel(const float* __restrict__ part,
                                  const float* __restrict__ kspart,
                                  unsigned short* __restrict__ ctxpad) {
  int i = blockIdx.x * 256 + threadIdx.x;  // < 8*96*320 = 245760
  int h = i / (96 * NFP);
  int rem = i % (96 * NFP);
  int r = rem / NFP, j = rem % NFP;
  float s = 0.f;
  if (r < 64) {
    #pragma unroll 4
    for (int kc = 0; kc < 32; ++kc)
      s += part[((long)(h * 32 + kc)) * 64 * NFP + r * NFP + j];
  } else if (r == 64) {
    #pragma unroll 4
    for (int kc = 0; kc < 32; ++kc)
      s += kspart[((long)(h * 32 + kc)) * NFP + j];
  }
  ctxpad[i] = f2bf(s);
}

// -------------------- attn_fused: phi(q) + qp@ctx + dinv --------------------

__global__ __launch_bounds__(256) void attn_fused_kernel(
    const unsigned short* __restrict__ Qp,
    const unsigned short* __restrict__ pb,
    const unsigned short* __restrict__ ctxpad,
    unsigned short* __restrict__ attn) {
  const int tid = threadIdx.x;
  const int wave = tid >> 6, lane = tid & 63;
  const int lr = lane & 15, lg = lane >> 4;
  const int h = blockIdx.z;
  const int m0 = blockIdx.x * 64;
  const int wbase = tid & 192;

  __shared__ uint4 smem[4096];
  auto sbuf = [&](int b) { return smem + b * 768; };
  uint4* Pf = smem + 1536;

  const unsigned short* Aq = Qp + (long)m0 * DQKV + h * DHEAD;
  const unsigned short* Ch = ctxpad + (long)h * 96 * NFP;

  auto stage_ctx = [&](int b, int kk) {
    #pragma unroll
    for (int e = 0; e < 3; ++e) {
      int chunk = e * 256 + tid;
      int r = chunk >> 3, c = chunk & 7;
      g2l16(Ch + (long)r * NFP + kk * 64 + (c ^ (r & 7)) * 8, sbuf(b) + e * 256 + wbase);
    }
  };

  #pragma unroll
  for (int e = 0; e < 2; ++e) {
    int chunk = e * 256 + tid;
    int r = chunk >> 3, c = chunk & 7;
    g2l16(Aq + (long)r * DQKV + (c ^ (r & 7)) * 8, sbuf(0) + e * 256 + wbase);
  }
  #pragma unroll
  for (int e = 0; e < 10; ++e) {
    int chunk = e * 256 + tid;
    int r = chunk >> 3, c = chunk & 7;
    g2l16(pb + (long)r * DHEAD + (c ^ (r & 7)) * 8, Pf + e * 256 + wbase);
  }
  __syncthreads();

  f32x4 acc[20] = {};
  float qs = 0.f;
  #pragma unroll
  for (int ks = 0; ks < 2; ++ks) {
    int rA = wave * 16 + lr;
    bf16x8 af = *(const bf16x8*)&sbuf(0)[rA * 8 + ((ks * 4 + lg) ^ (rA & 7))];
    #pragma unroll
    for (int i = 0; i < 8; ++i) {
      float f = bf2f((unsigned short)af[i]);
      qs += f * f;
    }
    #pragma unroll
    for (int j = 0; j < 20; ++j) {
      int rB = j * 16 + lr;
      bf16x8 bv = *(const bf16x8*)&Pf[rB * 8 + ((ks * 4 + lg) ^ (rB & 7))];
      acc[j] = __builtin_amdgcn_mfma_f32_16x16x32_bf16(af, bv, acc[j], 0, 0, 0);
    }
  }
  qs += __shfl_xor(qs, 16);
  qs += __shfl_xor(qs, 32);
  float dg[4];
  #pragma unroll
  for (int rg = 0; rg < 4; ++rg) dg[rg] = 0.0625f * __shfl(qs, lg * 4 + rg);

  float mrow[4];
  #pragma unroll
  for (int rg = 0; rg < 4; ++rg) mrow[rg] = -3.0e38f;
  #pragma unroll
  for (int j = 0; j < 17; ++j) {
    bool valid = (j < 16) || (lr < 10);
    if (valid) {
      #pragma unroll
      for (int rg = 0; rg < 4; ++rg) mrow[rg] = fmaxf(mrow[rg], acc[j][rg]);
    }
  }
  #pragma unroll
  for (int s = 1; s < 16; s <<= 1)
    #pragma unroll
    for (int rg = 0; rg < 4; ++rg) mrow[rg] = fmaxf(mrow[rg], __shfl_xor(mrow[rg], s));

  __syncthreads();
  stage_ctx(0, 0);

  unsigned short* Pu = (unsigned short*)Pf;
  const int prow = wave * 16 + lg * 4;
  #pragma unroll
  for (int j = 0; j < 20; ++j) {
    int col = j * 16 + lr;
    int kk = col >> 6, cc = (col >> 3) & 7;
    #pragma unroll
    for (int rg = 0; rg < 4; ++rg) {
      float v = 0.f;
      if (col < NF) v = RATIO * (__expf(acc[j][rg] - dg[rg] - mrow[rg]) + PEPS);
      int rw = prow + rg;
      int idx = ((kk * 512 + rw * 8 + (cc ^ (rw & 7))) << 3) + (col & 7);
      Pu[idx] = f2bf(v);
    }
  }
  __syncthreads();

  f32x4 acc2[6] = {};
  #pragma unroll
  for (int kk = 0; kk < 5; ++kk) {
    const int cur = kk & 1;
    if (kk + 1 < 5) stage_ctx(cur ^ 1, kk + 1);
    #pragma unroll
    for (int ks = 0; ks < 2; ++ks) {
      int rA = wave * 16 + lr;
      bf16x8 af = *(const bf16x8*)&Pf[kk * 512 + rA * 8 + ((ks * 4 + lg) ^ (rA & 7))];
      #pragma unroll
      for (int j = 0; j < 6; ++j) {
        int rB = j * 16 + lr;
        bf16x8 bv = *(const bf16x8*)&sbuf(cur)[rB * 8 + ((ks * 4 + lg) ^ (rB & 7))];
        acc2[j] = __builtin_amdgcn_mfma_f32_16x16x32_bf16(af, bv, acc2[j], 0, 0, 0);
      }
    }
    if (kk + 1 < 5) __syncthreads();
  }

  #pragma unroll
  for (int rg = 0; rg < 4; ++rg) {
    float dv = __shfl(acc2[4][rg], lane & 48);
    float inv = 1.0f / dv;
    int gm = m0 + wave * 16 + lg * 4 + rg;
    #pragma unroll
    for (int j = 0; j < 4; ++j) {
      attn[(long)gm * DMODEL + h * DHEAD + j * 16 + lr] = f2bf(acc2[j][rg] * inv);
    }
  }
}

// -------------------- launch --------------------

extern "C" void kernel_launch(void* const* d_in, const int* in_sizes, int n_in,
                              void* d_out, int out_size, void* d_ws, size_t ws_size,
                              hipStream_t stream) {
  const float* x    = (const float*)d_in[0];
  const float* proj = (const float*)d_in[1];
  const float* ln1g = (const float*)d_in[2];
  const float* ln1b = (const float*)d_in[3];
  const float* wq   = (const float*)d_in[4];
  const float* wk   = (const float*)d_in[5];
  const float* wv   = (const float*)d_in[6];
  const float* wo   = (const float*)d_in[7];
  const float* wob  = (const float*)d_in[8];
  const float* ln2g = (const float*)d_in[9];
  const float* ln2b = (const float*)d_in[10];
  const float* w1   = (const float*)d_in[11];
  const float* b1   = (const float*)d_in[12];
  const float* w2   = (const float*)d_in[13];
  const float* b2   = (const float*)d_in[14];

  char* ws = (char*)d_ws;
  unsigned short* wtqkv = (unsigned short*)(ws + 0);
  unsigned short* wot   = (unsigned short*)(ws + 1572864);
  unsigned short* w1t   = (unsigned short*)(ws + 2097152);
  unsigned short* w2t   = (unsigned short*)(ws + 4194304);
  unsigned short* pb    = (unsigned short*)(ws + 6291456);
  unsigned short* h_bf  = (unsigned short*)(ws + 6332416);
  unsigned short* qkv   = (unsigned short*)(ws + 14721024);
  unsigned* mk          = (unsigned*)(ws + 124297216);
  unsigned short* vT    = (unsigned short*)(ws + 124297472);
  float* part           = (float*)(ws + 132686080);
  float* kspart         = (float*)(ws + 153657600);
  unsigned short* ctxpad= (unsigned short*)(ws + 154978560);
  unsigned short* gbf   = (unsigned short*)(ws + 130468096);
  unsigned short* attn  = h_bf;
  unsigned short* h2    = qkv;
  float* xb             = (float*)d_out;

  dim3 blk(256);

  prep_kernel<<<3153, blk, 0, stream>>>(wq, wk, wv, wo, w1, w2, proj,
                                        wtqkv, wot, w1t, w2t, pb, mk);

  ln_kernel<<<N_SEQ, blk, 0, stream>>>(x, ln1g, ln1b, h_bf);

  // QKV: 256x256 8-phase, 192 blocks; v column-blocks (by=4,5) scatter to vT
  gemm8p_kernel<EPI_QKV><<<dim3(32, 6), dim3(512), 0, stream>>>(
      h_bf, 512, wtqkv, 512, qkv, DQKV, 512, nullptr, vT);

  kmax_kernel<<<dim3(128, 1, 8), blk, 0, stream>>>(qkv + 512, pb, mk);

  ctx_fused_kernel<<<dim3(32, 8), blk, 0, stream>>>(qkv + 512, pb, vT, mk, part, kspart);
  ctx_reduce_kernel<<<960, blk, 0, stream>>>(part, kspart, ctxpad);

  attn_fused_kernel<<<dim3(128, 1, 8), blk, 0, stream>>>(qkv, pb, ctxpad, attn);

  // WO: 512 blocks (BN=64)
  gemm_kernel<128, 64, 64, 32, EPI_BIAS_RES_F32><<<dim3(64, 8), blk, 0, stream>>>(
      attn, 512, wot, 512, xb, 512, 512, wob, x, 512);

  ln_kernel<<<N_SEQ, blk, 0, stream>>>(xb, ln2g, ln2b, h2);

  // FFN1: 256x256 8-phase, 256 blocks (1/CU exact)
  gemm8p_kernel<EPI_BIAS_GELU><<<dim3(32, 8), dim3(512), 0, stream>>>(
      h2, 512, w1t, 512, gbf, 2048, 512, b1, nullptr);

  // FFN2: 512 blocks (BN=64)
  gemm_kernel<128, 64, 64, 32, EPI_BIAS_RES_F32><<<dim3(64, 8), blk, 0, stream>>>(
      gbf, 2048, w2t, 2048, d_out, 512, 2048, b2, xb, 512);
}

// Round 10
// 179.844 us; speedup vs baseline: 1.0460x; 1.0460x over previous
//
#include <hip/hip_runtime.h>
#include <math.h>

// ---------------------------------------------------------------------------
// Performer encoder layer, MI355X round-10: revert 8-phase experiment;
// gemm8w = 256x64 8-wave counted-vmcnt GEMM (2 blocks/CU, 16 waves/CU) for
// QKV/FFN1/FFN2; kmax batched 4 subtiles/block; ln1 merged into prep;
// vmcnt counts corrected (round-8 latent race fixed).
// N=8192, D=512, H=8, DH=64, NF=266 (padded to NFP=320 = 5*64).
// Workspace layout: unchanged from round-8.
// ---------------------------------------------------------------------------

typedef __attribute__((ext_vector_type(8))) short bf16x8;
typedef __attribute__((ext_vector_type(4))) float f32x4;

#define N_SEQ 8192
#define DMODEL 512
#define DQKV 1536
#define NHEAD 8
#define DHEAD 64
#define NF 266
#define NFP 320
#define PEPS 1e-4f
#define LNEPS 1e-5f
#define RATIO 0.06131393694f

__device__ __forceinline__ unsigned short f2bf(float f) {
  unsigned u = __float_as_uint(f);
  u += 0x7FFFu + ((u >> 16) & 1u);
  return (unsigned short)(u >> 16);
}
__device__ __forceinline__ float bf2f(unsigned short b) {
  return __uint_as_float(((unsigned)b) << 16);
}
__device__ __forceinline__ unsigned enc_f32(float f) {
  unsigned i = __float_as_uint(f);
  return (i & 0x80000000u) ? ~i : (i | 0x80000000u);
}
__device__ __forceinline__ float dec_f32(unsigned u) {
  return (u & 0x80000000u) ? __uint_as_float(u & 0x7FFFFFFFu) : __uint_as_float(~u);
}

__device__ __forceinline__ void g2l16(const void* g, void* l) {
  __builtin_amdgcn_global_load_lds(
      (const __attribute__((address_space(1))) void*)g,
      (__attribute__((address_space(3))) void*)l, 16, 0, 0);
}

template <int N>
__device__ __forceinline__ void wait_vmcnt() {
  if constexpr (N == 0) asm volatile("s_waitcnt vmcnt(0)" ::: "memory");
  else if constexpr (N == 5) asm volatile("s_waitcnt vmcnt(5)" ::: "memory");
  else if constexpr (N == 6) asm volatile("s_waitcnt vmcnt(6)" ::: "memory");
}
__device__ __forceinline__ void wait_lgkm0() {
  asm volatile("s_waitcnt lgkmcnt(0)" ::: "memory");
}

// -------------------- fused prep + ln1 --------------------
// grid 11345: [0,3072) W transposes, [3072,3152) projb, 3152 mk,
// [3153,11345) ln1 rows.

__global__ __launch_bounds__(256) void prep_kernel(
    const float* __restrict__ wq, const float* __restrict__ wk,
    const float* __restrict__ wv, const float* __restrict__ wo,
    const float* __restrict__ w1, const float* __restrict__ w2,
    const float* __restrict__ proj,
    unsigned short* __restrict__ wtqkv, unsigned short* __restrict__ wot,
    unsigned short* __restrict__ w1t, unsigned short* __restrict__ w2t,
    unsigned short* __restrict__ pb, unsigned* __restrict__ mk,
    const float* __restrict__ x,
    const float* __restrict__ ln1g, const float* __restrict__ ln1b,
    unsigned short* __restrict__ h_bf) {
  int bid = blockIdx.x;
  if (bid < 3072) {
    const float* src; unsigned short* dst; int R, C, base;
    if (bid < 256)       { src = wq; dst = wtqkv;          R = 512;  C = 512;  base = 0; }
    else if (bid < 512)  { src = wk; dst = wtqkv + 262144; R = 512;  C = 512;  base = 256; }
    else if (bid < 768)  { src = wv; dst = wtqkv + 524288; R = 512;  C = 512;  base = 512; }
    else if (bid < 1024) { src = wo; dst = wot;            R = 512;  C = 512;  base = 768; }
    else if (bid < 2048) { src = w1; dst = w1t;            R = 512;  C = 2048; base = 1024; }
    else                 { src = w2; dst = w2t;            R = 2048; C = 512;  base = 2048; }
    int lb = bid - base;
    int nbx = C / 32;
    int c0 = (lb % nbx) * 32, r0 = (lb / nbx) * 32;
    __shared__ float tile[32][33];
    int tx = threadIdx.x & 31, ty = threadIdx.x >> 5;
    #pragma unroll
    for (int i = ty; i < 32; i += 8)
      tile[i][tx] = src[(long)(r0 + i) * C + c0 + tx];
    __syncthreads();
    #pragma unroll
    for (int i = ty; i < 32; i += 8)
      dst[(long)(c0 + i) * R + r0 + tx] = f2bf(tile[tx][i]);
  } else if (bid < 3152) {
    int id = (bid - 3072) * 256 + threadIdx.x;  // < 320*64
    int j = id >> 6;
    pb[id] = (j < NF) ? f2bf(proj[(long)j * 64 + (id & 63)] * 0.35355339059327373f)
                      : (unsigned short)0;
  } else if (bid == 3152) {
    if (threadIdx.x < NHEAD) mk[threadIdx.x] = 0x007FFFFFu;  // enc(-inf)
  } else {
    // ln1 row
    __shared__ float sred[4];
    int row = bid - 3153, t = threadIdx.x;
    float2 v = ((const float2*)(x + (long)row * DMODEL))[t];
    float s = v.x + v.y;
    #pragma unroll
    for (int m = 32; m >= 1; m >>= 1) s += __shfl_xor(s, m);
    if ((t & 63) == 0) sred[t >> 6] = s;
    __syncthreads();
    float mu = (sred[0] + sred[1] + sred[2] + sred[3]) * (1.0f / DMODEL);
    __syncthreads();
    float d0 = v.x - mu, d1 = v.y - mu;
    float q = d0 * d0 + d1 * d1;
    #pragma unroll
    for (int m = 32; m >= 1; m >>= 1) q += __shfl_xor(q, m);
    if ((t & 63) == 0) sred[t >> 6] = q;
    __syncthreads();
    float var = (sred[0] + sred[1] + sred[2] + sred[3]) * (1.0f / DMODEL);
    float inv = rsqrtf(var + LNEPS);
    int c = t * 2;
    unsigned short o0 = f2bf(d0 * inv * ln1g[c] + ln1b[c]);
    unsigned short o1 = f2bf(d1 * inv * ln1g[c + 1] + ln1b[c + 1]);
    ((unsigned*)(h_bf + (long)row * DMODEL))[t] = ((unsigned)o1 << 16) | o0;
  }
}

// -------------------- layernorm (ln2) --------------------

__global__ __launch_bounds__(256) void ln_kernel(const float* __restrict__ x,
                                                 const float* __restrict__ g,
                                                 const float* __restrict__ b,
                                                 unsigned short* __restrict__ out) {
  __shared__ float sred[4];
  int row = blockIdx.x, t = threadIdx.x;
  float2 v = ((const float2*)(x + (long)row * DMODEL))[t];
  float s = v.x + v.y;
  #pragma unroll
  for (int m = 32; m >= 1; m >>= 1) s += __shfl_xor(s, m);
  if ((t & 63) == 0) sred[t >> 6] = s;
  __syncthreads();
  float mu = (sred[0] + sred[1] + sred[2] + sred[3]) * (1.0f / DMODEL);
  __syncthreads();
  float d0 = v.x - mu, d1 = v.y - mu;
  float q = d0 * d0 + d1 * d1;
  #pragma unroll
  for (int m = 32; m >= 1; m >>= 1) q += __shfl_xor(q, m);
  if ((t & 63) == 0) sred[t >> 6] = q;
  __syncthreads();
  float var = (sred[0] + sred[1] + sred[2] + sred[3]) * (1.0f / DMODEL);
  float inv = rsqrtf(var + LNEPS);
  int c = t * 2;
  unsigned short o0 = f2bf(d0 * inv * g[c] + b[c]);
  unsigned short o1 = f2bf(d1 * inv * g[c + 1] + b[c + 1]);
  ((unsigned*)(out + (long)row * DMODEL))[t] = ((unsigned)o1 << 16) | o0;
}

enum { EPI_BF16 = 0, EPI_BIAS_RES_F32 = 2, EPI_BIAS_GELU = 3, EPI_QKV = 4 };

// ---------------- gemm8w: 256x64 8-wave counted-vmcnt GEMM ------------------
// 512 threads = 8 waves (4M x 2N), WM=64, WN=32, BK=64, 80KB dbuf LDS
// (2 blocks/CU = 16 waves/CU). S=5 loads/thread/stage; pipe never drains.

template <int EPI>
__global__ __launch_bounds__(512, 4) void gemm8w_kernel(
    const unsigned short* __restrict__ A, int lda,
    const unsigned short* __restrict__ Bt, int ldb,
    void* __restrict__ Cv, int ldc,
    int K,
    const float* __restrict__ bias,
    const float* __restrict__ res, int ldr,
    unsigned short* __restrict__ vt) {
  constexpr int MR = 4, NR = 2;
  constexpr int S = 5;
  const int tid = threadIdx.x;
  const int wave = tid >> 6, lane = tid & 63;
  const int lr = lane & 15, lg = lane >> 4;
  const int wr = wave >> 1, wc = wave & 1;
  const int m0 = blockIdx.x * 256, n0 = blockIdx.y * 64;

  __shared__ uint4 a_s[2][2048];
  __shared__ uint4 b_s[2][512];

  const unsigned short* asrc[4];
  #pragma unroll
  for (int e = 0; e < 4; ++e) {
    int chunk = e * 512 + tid;
    int r = chunk >> 3, c = chunk & 7;
    asrc[e] = A + (long)(m0 + r) * lda + (c ^ (r & 7)) * 8;
  }
  const unsigned short* bsrc;
  {
    int r = tid >> 3, c = tid & 7;
    bsrc = Bt + (long)(n0 + r) * ldb + (c ^ (r & 7)) * 8;
  }
  const int wbase = tid & 448;

  f32x4 acc[MR][NR] = {};

  auto stage = [&](int buf, int t) {
    #pragma unroll
    for (int e = 0; e < 4; ++e)
      g2l16(asrc[e] + t * 64, &a_s[buf][e * 512 + wbase]);
    g2l16(bsrc + t * 64, &b_s[buf][wbase]);
  };
  auto compute = [&](int buf) {
    #pragma unroll
    for (int ks = 0; ks < 2; ++ks) {
      bf16x8 af[MR], bv[NR];
      #pragma unroll
      for (int i = 0; i < MR; ++i) {
        int r = wr * 64 + i * 16 + lr;
        af[i] = *(const bf16x8*)&a_s[buf][r * 8 + ((ks * 4 + lg) ^ (r & 7))];
      }
      #pragma unroll
      for (int j = 0; j < NR; ++j) {
        int r = wc * 32 + j * 16 + lr;
        bv[j] = *(const bf16x8*)&b_s[buf][r * 8 + ((ks * 4 + lg) ^ (r & 7))];
      }
      #pragma unroll
      for (int i = 0; i < MR; ++i)
        #pragma unroll
        for (int j = 0; j < NR; ++j)
          acc[i][j] = __builtin_amdgcn_mfma_f32_16x16x32_bf16(af[i], bv[j], acc[i][j], 0, 0, 0);
    }
  };

  const int NT = K >> 6;
  stage(0, 0);
  stage(1, 1);
  wait_vmcnt<S>();  // tile 0 fully landed (tile 1 in flight)
  __builtin_amdgcn_s_barrier();

  int cur = 0;
  for (int t = 0; t < NT; ++t) {
    compute(cur);
    if (t + 1 < NT) {
      wait_lgkm0();
      __builtin_amdgcn_s_barrier();
      if (t + 2 < NT) {
        stage(cur, t + 2);
        wait_vmcnt<S>();  // tile t+1 landed; t+2 in flight
      } else {
        wait_vmcnt<0>();
      }
      __builtin_amdgcn_s_barrier();
    }
    cur ^= 1;
  }

  #pragma unroll
  for (int i = 0; i < MR; ++i) {
    #pragma unroll
    for (int j = 0; j < NR; ++j) {
      int gn = n0 + wc * 32 + j * 16 + lr;
      int gm0 = m0 + wr * 64 + i * 16 + lg * 4;
      if (EPI == EPI_QKV && gn >= 1024) {
        int d = gn - 1024;
        uint2 u;
        u.x = (unsigned)f2bf(acc[i][j][0]) | ((unsigned)f2bf(acc[i][j][1]) << 16);
        u.y = (unsigned)f2bf(acc[i][j][2]) | ((unsigned)f2bf(acc[i][j][3]) << 16);
        *(uint2*)(vt + (long)d * N_SEQ + gm0) = u;
        continue;
      }
      #pragma unroll
      for (int rg = 0; rg < 4; ++rg) {
        int gm = gm0 + rg;
        float v = acc[i][j][rg];
        if (EPI == EPI_BF16 || EPI == EPI_QKV) {
          ((unsigned short*)Cv)[(long)gm * ldc + gn] = f2bf(v);
        } else if (EPI == EPI_BIAS_RES_F32) {
          v += bias[gn] + res[(long)gm * ldr + gn];
          ((float*)Cv)[(long)gm * ldc + gn] = v;
        } else if (EPI == EPI_BIAS_GELU) {
          v += bias[gn];
          float t3 = 0.7978845608028654f * (v + 0.044715f * v * v * v);
          v = v / (1.0f + __expf(-2.0f * t3));  // 0.5v(1+tanh(t3))
          ((unsigned short*)Cv)[(long)gm * ldc + gn] = f2bf(v);
        }
      }
    }
  }
}

// -------- counted-vmcnt double-buffered 128x64 4-wave GEMM (WO) -------------

template <int BM, int BN, int WM, int WN, int EPI>
__global__ __launch_bounds__(256) void gemm_kernel(
    const unsigned short* __restrict__ A, int lda,
    const unsigned short* __restrict__ Bt, int ldb,
    void* __restrict__ Cv, int ldc,
    int K,
    const float* __restrict__ bias,
    const float* __restrict__ res, int ldr) {
  static_assert((BM / WM) * (BN / WN) == 4, "need 4 waves");
  constexpr int MR = WM / 16, NR = WN / 16;
  constexpr int WNN = BN / WN;
  constexpr int AIT = BM * 8 / 256;
  constexpr int BIT = BN * 8 / 256;
  constexpr int S = AIT + BIT;
  static_assert(S == 6, "wait count tuned for BM=128,BN=64");
  const int tid = threadIdx.x;
  const int wave = tid >> 6, lane = tid & 63;
  const int lr = lane & 15, lg = lane >> 4;
  const int wr = wave / WNN, wc = wave % WNN;
  const int m0 = blockIdx.x * BM, n0 = blockIdx.y * BN;

  __shared__ uint4 a_s[2][BM * 8];
  __shared__ uint4 b_s[2][BN * 8];

  const unsigned short* asrc[AIT];
  #pragma unroll
  for (int e = 0; e < AIT; ++e) {
    int chunk = e * 256 + tid;
    int r = chunk >> 3, c = chunk & 7;
    asrc[e] = A + (long)(m0 + r) * lda + (c ^ (r & 7)) * 8;
  }
  const unsigned short* bsrc[BIT];
  #pragma unroll
  for (int e = 0; e < BIT; ++e) {
    int chunk = e * 256 + tid;
    int r = chunk >> 3, c = chunk & 7;
    bsrc[e] = Bt + (long)(n0 + r) * ldb + (c ^ (r & 7)) * 8;
  }
  const int wbase = tid & 192;

  f32x4 acc[MR][NR] = {};

  auto stage = [&](int buf, int t) {
    #pragma unroll
    for (int e = 0; e < AIT; ++e)
      g2l16(asrc[e] + t * 64, &a_s[buf][e * 256 + wbase]);
    #pragma unroll
    for (int e = 0; e < BIT; ++e)
      g2l16(bsrc[e] + t * 64, &b_s[buf][e * 256 + wbase]);
  };
  auto compute = [&](int buf) {
    #pragma unroll
    for (int ks = 0; ks < 2; ++ks) {
      bf16x8 af[MR], bv[NR];
      #pragma unroll
      for (int i = 0; i < MR; ++i) {
        int r = wr * WM + i * 16 + lr;
        af[i] = *(const bf16x8*)&a_s[buf][r * 8 + ((ks * 4 + lg) ^ (r & 7))];
      }
      #pragma unroll
      for (int j = 0; j < NR; ++j) {
        int r = wc * WN + j * 16 + lr;
        bv[j] = *(const bf16x8*)&b_s[buf][r * 8 + ((ks * 4 + lg) ^ (r & 7))];
      }
      #pragma unroll
      for (int i = 0; i < MR; ++i)
        #pragma unroll
        for (int j = 0; j < NR; ++j)
          acc[i][j] = __builtin_amdgcn_mfma_f32_16x16x32_bf16(af[i], bv[j], acc[i][j], 0, 0, 0);
    }
  };

  const int NT = K >> 6;
  stage(0, 0);
  stage(1, 1);
  wait_vmcnt<6>();
  __builtin_amdgcn_s_barrier();

  int cur = 0;
  for (int t = 0; t < NT; ++t) {
    compute(cur);
    if (t + 1 < NT) {
      wait_lgkm0();
      __builtin_amdgcn_s_barrier();
      if (t + 2 < NT) {
        stage(cur, t + 2);
        wait_vmcnt<6>();
      } else {
        wait_vmcnt<0>();
      }
      __builtin_amdgcn_s_barrier();
    }
    cur ^= 1;
  }

  #pragma unroll
  for (int i = 0; i < MR; ++i) {
    #pragma unroll
    for (int j = 0; j < NR; ++j) {
      int gn = n0 + wc * WN + j * 16 + lr;
      #pragma unroll
      for (int rg = 0; rg < 4; ++rg) {
        int gm = m0 + wr * WM + i * 16 + lg * 4 + rg;
        float v = acc[i][j][rg];
        if (EPI == EPI_BF16) {
          ((unsigned short*)Cv)[(long)gm * ldc + gn] = f2bf(v);
        } else if (EPI == EPI_BIAS_RES_F32) {
          v += bias[gn] + res[(long)gm * ldr + gn];
          ((float*)Cv)[(long)gm * ldc + gn] = v;
        } else if (EPI == EPI_BIAS_GELU) {
          v += bias[gn];
          float t3 = 0.7978845608028654f * (v + 0.044715f * v * v * v);
          v = v / (1.0f + __expf(-2.0f * t3));
          ((unsigned short*)Cv)[(long)gm * ldc + gn] = f2bf(v);
        }
      }
    }
  }
}

// ------------- kmax: global max of dd(k) per head, 256 rows/block -----------
// grid (32, 1, 8); pb staged once, a-tiles double-buffered (4 subs).

__global__ __launch_bounds__(256) void kmax_kernel(
    const unsigned short* __restrict__ Kp,
    const unsigned short* __restrict__ pb,
    unsigned* __restrict__ mk) {
  const int tid = threadIdx.x;
  const int wave = tid >> 6, lane = tid & 63;
  const int lr = lane & 15, lg = lane >> 4;
  const int h = blockIdx.z;
  const int m0 = blockIdx.x * 256;
  const int wbase = tid & 192;

  __shared__ uint4 pbs[2560];
  __shared__ uint4 abuf[2][512];
  __shared__ float sred[4];

  #pragma unroll
  for (int e = 0; e < 10; ++e) {
    int chunk = e * 256 + tid;
    int r = chunk >> 3, c = chunk & 7;
    g2l16(pb + (long)r * DHEAD + (c ^ (r & 7)) * 8, pbs + e * 256 + wbase);
  }
  auto stage_a = [&](int b, int sub) {
    #pragma unroll
    for (int e = 0; e < 2; ++e) {
      int chunk = e * 256 + tid;
      int r = chunk >> 3, c = chunk & 7;
      g2l16(Kp + (long)(m0 + sub * 64 + r) * DQKV + h * DHEAD + (c ^ (r & 7)) * 8,
            abuf[b] + e * 256 + wbase);
    }
  };

  stage_a(0, 0);
  __syncthreads();

  float m = -3.0e38f;
  for (int sub = 0; sub < 4; ++sub) {
    const int cur = sub & 1;
    if (sub + 1 < 4) stage_a(cur ^ 1, sub + 1);

    f32x4 acc[17] = {};
    #pragma unroll
    for (int ks = 0; ks < 2; ++ks) {
      int rA = wave * 16 + lr;
      bf16x8 af = *(const bf16x8*)&abuf[cur][rA * 8 + ((ks * 4 + lg) ^ (rA & 7))];
      #pragma unroll
      for (int j = 0; j < 17; ++j) {
        int rB = j * 16 + lr;
        bf16x8 bv = *(const bf16x8*)&pbs[rB * 8 + ((ks * 4 + lg) ^ (rB & 7))];
        acc[j] = __builtin_amdgcn_mfma_f32_16x16x32_bf16(af, bv, acc[j], 0, 0, 0);
      }
    }
    #pragma unroll
    for (int j = 0; j < 17; ++j) {
      bool valid = (j < 16) || (lr < 10);  // col = j*16+lr < 266
      if (valid) {
        #pragma unroll
        for (int rg = 0; rg < 4; ++rg) m = fmaxf(m, acc[j][rg]);
      }
    }
    if (sub + 1 < 4) __syncthreads();  // next a-tile landed; cur reads done
  }

  #pragma unroll
  for (int s = 1; s < 64; s <<= 1) m = fmaxf(m, __shfl_xor(m, s));
  if (lane == 0) sred[wave] = m;
  __syncthreads();
  if (tid == 0) {
    float mm = fmaxf(fmaxf(sred[0], sred[1]), fmaxf(sred[2], sred[3]));
    atomicMax(&mk[h], enc_f32(mm));
  }
}

// -------------------- ctx_fused: phi(k) + kp^T v + colsums -------------------

__global__ __launch_bounds__(256) void ctx_fused_kernel(
    const unsigned short* __restrict__ Kp,
    const unsigned short* __restrict__ pb,
    const unsigned short* __restrict__ vT,
    const unsigned* __restrict__ mk,
    float* __restrict__ part,
    float* __restrict__ kspart) {
  const int tid = threadIdx.x;
  const int wave = tid >> 6, lane = tid & 63;
  const int lr = lane & 15, lg = lane >> 4;
  const int kc = blockIdx.x, h = blockIdx.y;
  const int wbase = tid & 192;

  __shared__ uint4 smem[7168];
  uint4* pbs = smem;
  auto kbuf = [&](int b) { return smem + 2560 + b * 512; };
  auto vbuf = [&](int b) { return smem + 3584 + b * 512; };
  uint4* Pt = smem + 4608;

  #pragma unroll
  for (int e = 0; e < 10; ++e) {
    int chunk = e * 256 + tid;
    int r = chunk >> 3, c = chunk & 7;
    g2l16(pb + (long)r * DHEAD + (c ^ (r & 7)) * 8, pbs + e * 256 + wbase);
  }

  auto stage_kv = [&](int b, int sub) {
    int n0 = kc * 256 + sub * 64;
    #pragma unroll
    for (int e = 0; e < 2; ++e) {
      int chunk = e * 256 + tid;
      int r = chunk >> 3, c = chunk & 7;
      g2l16(Kp + (long)(n0 + r) * DQKV + h * DHEAD + (c ^ (r & 7)) * 8,
            kbuf(b) + e * 256 + wbase);
      g2l16(vT + ((long)h * DHEAD + r) * N_SEQ + n0 + (c ^ (r & 7)) * 8,
            vbuf(b) + e * 256 + wbase);
    }
  };

  const float mh = dec_f32(mk[h]);
  f32x4 acc2[2][10] = {};
  float colacc[20];
  #pragma unroll
  for (int j = 0; j < 20; ++j) colacc[j] = 0.f;

  const int wr = wave >> 1, wc = wave & 1;

  stage_kv(0, 0);
  for (int sub = 0; sub < 4; ++sub) {
    const int cur = sub & 1;
    __syncthreads();
    if (sub + 1 < 4) stage_kv(cur ^ 1, sub + 1);

    f32x4 acc[20] = {};
    float qs = 0.f;
    #pragma unroll
    for (int ks = 0; ks < 2; ++ks) {
      int rA = wave * 16 + lr;
      bf16x8 af = *(const bf16x8*)&kbuf(cur)[rA * 8 + ((ks * 4 + lg) ^ (rA & 7))];
      #pragma unroll
      for (int i = 0; i < 8; ++i) {
        float f = bf2f((unsigned short)af[i]);
        qs += f * f;
      }
      #pragma unroll
      for (int j = 0; j < 20; ++j) {
        int rB = j * 16 + lr;
        bf16x8 bv = *(const bf16x8*)&pbs[rB * 8 + ((ks * 4 + lg) ^ (rB & 7))];
        acc[j] = __builtin_amdgcn_mfma_f32_16x16x32_bf16(af, bv, acc[j], 0, 0, 0);
      }
    }
    qs += __shfl_xor(qs, 16);
    qs += __shfl_xor(qs, 32);
    float dg[4];
    #pragma unroll
    for (int rg = 0; rg < 4; ++rg) dg[rg] = 0.0625f * __shfl(qs, lg * 4 + rg);

    __syncthreads();

    unsigned short* Ptu = (unsigned short*)Pt;
    const int nrow = wave * 16 + lg * 4;
    #pragma unroll
    for (int j = 0; j < 20; ++j) {
      int colj = j * 16 + lr;
      #pragma unroll
      for (int rg = 0; rg < 4; ++rg) {
        float v = 0.f;
        if (colj < NF) v = RATIO * (__expf(acc[j][rg] - dg[rg] - mh) + PEPS);
        colacc[j] += v;
        int nr = nrow + rg;
        int idx = ((colj * 8 + ((nr >> 3) ^ (colj & 7))) << 3) + (nr & 7);
        Ptu[idx] = f2bf(v);
      }
    }
    __syncthreads();

    #pragma unroll
    for (int ks = 0; ks < 2; ++ks) {
      bf16x8 af[2], bv[10];
      #pragma unroll
      for (int i = 0; i < 2; ++i) {
        int r = wr * 32 + i * 16 + lr;
        af[i] = *(const bf16x8*)&vbuf(cur)[r * 8 + ((ks * 4 + lg) ^ (r & 7))];
      }
      #pragma unroll
      for (int j = 0; j < 10; ++j) {
        int r = wc * 160 + j * 16 + lr;
        bv[j] = *(const bf16x8*)&Pt[r * 8 + ((ks * 4 + lg) ^ (r & 7))];
      }
      #pragma unroll
      for (int i = 0; i < 2; ++i)
        #pragma unroll
        for (int j = 0; j < 10; ++j)
          acc2[i][j] = __builtin_amdgcn_mfma_f32_16x16x32_bf16(af[i], bv[j], acc2[i][j], 0, 0, 0);
    }
  }

  float* pbase = part + ((long)(h * 32 + kc)) * 64 * NFP;
  #pragma unroll
  for (int i = 0; i < 2; ++i) {
    #pragma unroll
    for (int j = 0; j < 10; ++j) {
      int gn = wc * 160 + j * 16 + lr;
      #pragma unroll
      for (int rg = 0; rg < 4; ++rg) {
        int gm = wr * 32 + i * 16 + lg * 4 + rg;
        pbase[(long)gm * NFP + gn] = acc2[i][j][rg];
      }
    }
  }

  __syncthreads();
  float* kls = (float*)Pt;
  #pragma unroll
  for (int j = 0; j < 20; ++j) {
    float cs = colacc[j];
    cs += __shfl_xor(cs, 16);
    cs += __shfl_xor(cs, 32);
    if (lg == 0) kls[wave * NFP + j * 16 + lr] = cs;
  }
  __syncthreads();
  for (int c0 = tid; c0 < NFP; c0 += 256) {
    kspart[((long)(h * 32 + kc)) * NFP + c0] =
        kls[c0] + kls[NFP + c0] + kls[2 * NFP + c0] + kls[3 * NFP + c0];
  }
}

// -------------------- ctxpad build --------------------

__global__ void ctx_reduce_kernel(const float* __restrict__ part,
                                  const float* __restrict__ kspart,
                                  unsigned short* __restrict__ ctxpad) {
  int i = blockIdx.x * 256 + threadIdx.x;  // < 8*96*320 = 245760
  int h = i / (96 * NFP);
  int rem = i % (96 * NFP);
  int r = rem / NFP, j = rem % NFP;
  float s = 0.f;
  if (r < 64) {
    #pragma unroll 4
    for (int kc = 0; kc < 32; ++kc)
      s += part[((long)(h * 32 + kc)) * 64 * NFP + r * NFP + j];
  } else if (r == 64) {
    #pragma unroll 4
    for (int kc = 0; kc < 32; ++kc)
      s += kspart[((long)(h * 32 + kc)) * NFP + j];
  }
  ctxpad[i] = f2bf(s);
}

// -------------------- attn_fused: phi(q) + qp@ctx + dinv --------------------

__global__ __launch_bounds__(256) void attn_fused_kernel(
    const unsigned short* __restrict__ Qp,
    const unsigned short* __restrict__ pb,
    const unsigned short* __restrict__ ctxpad,
    unsigned short* __restrict__ attn) {
  const int tid = threadIdx.x;
  const int wave = tid >> 6, lane = tid & 63;
  const int lr = lane & 15, lg = lane >> 4;
  const int h = blockIdx.z;
  const int m0 = blockIdx.x * 64;
  const int wbase = tid & 192;

  __shared__ uint4 smem[4096];
  auto sbuf = [&](int b) { return smem + b * 768; };
  uint4* Pf = smem + 1536;

  const unsigned short* Aq = Qp + (long)m0 * DQKV + h * DHEAD;
  const unsigned short* Ch = ctxpad + (long)h * 96 * NFP;

  auto stage_ctx = [&](int b, int kk) {
    #pragma unroll
    for (int e = 0; e < 3; ++e) {
      int chunk = e * 256 + tid;
      int r = chunk >> 3, c = chunk & 7;
      g2l16(Ch + (long)r * NFP + kk * 64 + (c ^ (r & 7)) * 8, sbuf(b) + e * 256 + wbase);
    }
  };

  #pragma unroll
  for (int e = 0; e < 2; ++e) {
    int chunk = e * 256 + tid;
    int r = chunk >> 3, c = chunk & 7;
    g2l16(Aq + (long)r * DQKV + (c ^ (r & 7)) * 8, sbuf(0) + e * 256 + wbase);
  }
  #pragma unroll
  for (int e = 0; e < 10; ++e) {
    int chunk = e * 256 + tid;
    int r = chunk >> 3, c = chunk & 7;
    g2l16(pb + (long)r * DHEAD + (c ^ (r & 7)) * 8, Pf + e * 256 + wbase);
  }
  __syncthreads();

  f32x4 acc[20] = {};
  float qs = 0.f;
  #pragma unroll
  for (int ks = 0; ks < 2; ++ks) {
    int rA = wave * 16 + lr;
    bf16x8 af = *(const bf16x8*)&sbuf(0)[rA * 8 + ((ks * 4 + lg) ^ (rA & 7))];
    #pragma unroll
    for (int i = 0; i < 8; ++i) {
      float f = bf2f((unsigned short)af[i]);
      qs += f * f;
    }
    #pragma unroll
    for (int j = 0; j < 20; ++j) {
      int rB = j * 16 + lr;
      bf16x8 bv = *(const bf16x8*)&Pf[rB * 8 + ((ks * 4 + lg) ^ (rB & 7))];
      acc[j] = __builtin_amdgcn_mfma_f32_16x16x32_bf16(af, bv, acc[j], 0, 0, 0);
    }
  }
  qs += __shfl_xor(qs, 16);
  qs += __shfl_xor(qs, 32);
  float dg[4];
  #pragma unroll
  for (int rg = 0; rg < 4; ++rg) dg[rg] = 0.0625f * __shfl(qs, lg * 4 + rg);

  float mrow[4];
  #pragma unroll
  for (int rg = 0; rg < 4; ++rg) mrow[rg] = -3.0e38f;
  #pragma unroll
  for (int j = 0; j < 17; ++j) {
    bool valid = (j < 16) || (lr < 10);
    if (valid) {
      #pragma unroll
      for (int rg = 0; rg < 4; ++rg) mrow[rg] = fmaxf(mrow[rg], acc[j][rg]);
    }
  }
  #pragma unroll
  for (int s = 1; s < 16; s <<= 1)
    #pragma unroll
    for (int rg = 0; rg < 4; ++rg) mrow[rg] = fmaxf(mrow[rg], __shfl_xor(mrow[rg], s));

  __syncthreads();
  stage_ctx(0, 0);

  unsigned short* Pu = (unsigned short*)Pf;
  const int prow = wave * 16 + lg * 4;
  #pragma unroll
  for (int j = 0; j < 20; ++j) {
    int col = j * 16 + lr;
    int kk = col >> 6, cc = (col >> 3) & 7;
    #pragma unroll
    for (int rg = 0; rg < 4; ++rg) {
      float v = 0.f;
      if (col < NF) v = RATIO * (__expf(acc[j][rg] - dg[rg] - mrow[rg]) + PEPS);
      int rw = prow + rg;
      int idx = ((kk * 512 + rw * 8 + (cc ^ (rw & 7))) << 3) + (col & 7);
      Pu[idx] = f2bf(v);
    }
  }
  __syncthreads();

  f32x4 acc2[6] = {};
  #pragma unroll
  for (int kk = 0; kk < 5; ++kk) {
    const int cur = kk & 1;
    if (kk + 1 < 5) stage_ctx(cur ^ 1, kk + 1);
    #pragma unroll
    for (int ks = 0; ks < 2; ++ks) {
      int rA = wave * 16 + lr;
      bf16x8 af = *(const bf16x8*)&Pf[kk * 512 + rA * 8 + ((ks * 4 + lg) ^ (rA & 7))];
      #pragma unroll
      for (int j = 0; j < 6; ++j) {
        int rB = j * 16 + lr;
        bf16x8 bv = *(const bf16x8*)&sbuf(cur)[rB * 8 + ((ks * 4 + lg) ^ (rB & 7))];
        acc2[j] = __builtin_amdgcn_mfma_f32_16x16x32_bf16(af, bv, acc2[j], 0, 0, 0);
      }
    }
    if (kk + 1 < 5) __syncthreads();
  }

  #pragma unroll
  for (int rg = 0; rg < 4; ++rg) {
    float dv = __shfl(acc2[4][rg], lane & 48);
    float inv = 1.0f / dv;
    int gm = m0 + wave * 16 + lg * 4 + rg;
    #pragma unroll
    for (int j = 0; j < 4; ++j) {
      attn[(long)gm * DMODEL + h * DHEAD + j * 16 + lr] = f2bf(acc2[j][rg] * inv);
    }
  }
}

// -------------------- launch --------------------

extern "C" void kernel_launch(void* const* d_in, const int* in_sizes, int n_in,
                              void* d_out, int out_size, void* d_ws, size_t ws_size,
                              hipStream_t stream) {
  const float* x    = (const float*)d_in[0];
  const float* proj = (const float*)d_in[1];
  const float* ln1g = (const float*)d_in[2];
  const float* ln1b = (const float*)d_in[3];
  const float* wq   = (const float*)d_in[4];
  const float* wk   = (const float*)d_in[5];
  const float* wv   = (const float*)d_in[6];
  const float* wo   = (const float*)d_in[7];
  const float* wob  = (const float*)d_in[8];
  const float* ln2g = (const float*)d_in[9];
  const float* ln2b = (const float*)d_in[10];
  const float* w1   = (const float*)d_in[11];
  const float* b1   = (const float*)d_in[12];
  const float* w2   = (const float*)d_in[13];
  const float* b2   = (const float*)d_in[14];

  char* ws = (char*)d_ws;
  unsigned short* wtqkv = (unsigned short*)(ws + 0);
  unsigned short* wot   = (unsigned short*)(ws + 1572864);
  unsigned short* w1t   = (unsigned short*)(ws + 2097152);
  unsigned short* w2t   = (unsigned short*)(ws + 4194304);
  unsigned short* pb    = (unsigned short*)(ws + 6291456);
  unsigned short* h_bf  = (unsigned short*)(ws + 6332416);
  unsigned short* qkv   = (unsigned short*)(ws + 14721024);
  unsigned* mk          = (unsigned*)(ws + 124297216);
  unsigned short* vT    = (unsigned short*)(ws + 124297472);
  float* part           = (float*)(ws + 132686080);
  float* kspart         = (float*)(ws + 153657600);
  unsigned short* ctxpad= (unsigned short*)(ws + 154978560);
  unsigned short* gbf   = (unsigned short*)(ws + 130468096);
  unsigned short* attn  = h_bf;
  unsigned short* h2    = qkv;
  float* xb             = (float*)d_out;

  dim3 blk(256);

  prep_kernel<<<11345, blk, 0, stream>>>(wq, wk, wv, wo, w1, w2, proj,
                                         wtqkv, wot, w1t, w2t, pb, mk,
                                         x, ln1g, ln1b, h_bf);

  // QKV: 256x64, 768 blocks; v column-blocks (by>=16) scatter to vT
  gemm8w_kernel<EPI_QKV><<<dim3(32, 24), dim3(512), 0, stream>>>(
      h_bf, 512, wtqkv, 512, qkv, DQKV, 512, nullptr, nullptr, 0, vT);

  kmax_kernel<<<dim3(32, 1, 8), blk, 0, stream>>>(qkv + 512, pb, mk);

  ctx_fused_kernel<<<dim3(32, 8), blk, 0, stream>>>(qkv + 512, pb, vT, mk, part, kspart);
  ctx_reduce_kernel<<<960, blk, 0, stream>>>(part, kspart, ctxpad);

  attn_fused_kernel<<<dim3(128, 1, 8), blk, 0, stream>>>(qkv, pb, ctxpad, attn);

  // WO: 128x64, 512 blocks
  gemm_kernel<128, 64, 64, 32, EPI_BIAS_RES_F32><<<dim3(64, 8), blk, 0, stream>>>(
      attn, 512, wot, 512, xb, 512, 512, wob, x, 512);

  ln_kernel<<<N_SEQ, blk, 0, stream>>>(xb, ln2g, ln2b, h2);

  // FFN1: 256x64, 1024 blocks
  gemm8w_kernel<EPI_BIAS_GELU><<<dim3(32, 32), dim3(512), 0, stream>>>(
      h2, 512, w1t, 512, gbf, 2048, 512, b1, nullptr, 0, nullptr);

  // FFN2: 256x64, 256 blocks, K=2048
  gemm8w_kernel<EPI_BIAS_RES_F32><<<dim3(32, 8), dim3(512), 0, stream>>>(
      gbf, 2048, w2t, 2048, d_out, 512, 2048, b2, xb, 512, nullptr);
}

// Round 11
// 168.357 us; speedup vs baseline: 1.1173x; 1.0682x over previous
//
#include <hip/hip_runtime.h>
#include <math.h>

// ---------------------------------------------------------------------------
// Performer encoder layer, MI355X round-11: FFN2 back to 128x64 (3 blocks/CU),
// ctx_fused slimmed to 76KB LDS (2 blocks/CU: single-buffer kv + Pt j-split),
// per-wave LayerNorm (no LDS). QKV/FFN1 stay on gemm8w.
// N=8192, D=512, H=8, DH=64, NF=266 (padded to NFP=320 = 5*64).
// Workspace layout: unchanged from round-8.
// ---------------------------------------------------------------------------

typedef __attribute__((ext_vector_type(8))) short bf16x8;
typedef __attribute__((ext_vector_type(4))) float f32x4;

#define N_SEQ 8192
#define DMODEL 512
#define DQKV 1536
#define NHEAD 8
#define DHEAD 64
#define NF 266
#define NFP 320
#define PEPS 1e-4f
#define LNEPS 1e-5f
#define RATIO 0.06131393694f

__device__ __forceinline__ unsigned short f2bf(float f) {
  unsigned u = __float_as_uint(f);
  u += 0x7FFFu + ((u >> 16) & 1u);
  return (unsigned short)(u >> 16);
}
__device__ __forceinline__ float bf2f(unsigned short b) {
  return __uint_as_float(((unsigned)b) << 16);
}
__device__ __forceinline__ unsigned enc_f32(float f) {
  unsigned i = __float_as_uint(f);
  return (i & 0x80000000u) ? ~i : (i | 0x80000000u);
}
__device__ __forceinline__ float dec_f32(unsigned u) {
  return (u & 0x80000000u) ? __uint_as_float(u & 0x7FFFFFFFu) : __uint_as_float(~u);
}

__device__ __forceinline__ void g2l16(const void* g, void* l) {
  __builtin_amdgcn_global_load_lds(
      (const __attribute__((address_space(1))) void*)g,
      (__attribute__((address_space(3))) void*)l, 16, 0, 0);
}

template <int N>
__device__ __forceinline__ void wait_vmcnt() {
  if constexpr (N == 0) asm volatile("s_waitcnt vmcnt(0)" ::: "memory");
  else if constexpr (N == 5) asm volatile("s_waitcnt vmcnt(5)" ::: "memory");
  else if constexpr (N == 6) asm volatile("s_waitcnt vmcnt(6)" ::: "memory");
}
__device__ __forceinline__ void wait_lgkm0() {
  asm volatile("s_waitcnt lgkmcnt(0)" ::: "memory");
}

// -------------------- per-wave LayerNorm body (1 row / wave) ----------------

__device__ __forceinline__ void ln_row(const float* __restrict__ x,
                                       const float* __restrict__ g,
                                       const float* __restrict__ b,
                                       unsigned short* __restrict__ out,
                                       long row, int lane) {
  const float4* xr = (const float4*)(x + row * DMODEL);
  float4 v0 = xr[lane * 2], v1 = xr[lane * 2 + 1];
  float s = v0.x + v0.y + v0.z + v0.w + v1.x + v1.y + v1.z + v1.w;
  #pragma unroll
  for (int m = 32; m >= 1; m >>= 1) s += __shfl_xor(s, m);
  float mu = s * (1.0f / DMODEL);
  float d[8] = {v0.x - mu, v0.y - mu, v0.z - mu, v0.w - mu,
                v1.x - mu, v1.y - mu, v1.z - mu, v1.w - mu};
  float q = 0.f;
  #pragma unroll
  for (int k = 0; k < 8; ++k) q += d[k] * d[k];
  #pragma unroll
  for (int m = 32; m >= 1; m >>= 1) q += __shfl_xor(q, m);
  float inv = rsqrtf(q * (1.0f / DMODEL) + LNEPS);
  const float4* gr = (const float4*)g;
  const float4* br = (const float4*)b;
  float4 g0 = gr[lane * 2], g1 = gr[lane * 2 + 1];
  float4 b0 = br[lane * 2], b1 = br[lane * 2 + 1];
  float gg[8] = {g0.x, g0.y, g0.z, g0.w, g1.x, g1.y, g1.z, g1.w};
  float bb[8] = {b0.x, b0.y, b0.z, b0.w, b1.x, b1.y, b1.z, b1.w};
  unsigned short o[8];
  #pragma unroll
  for (int k = 0; k < 8; ++k) o[k] = f2bf(d[k] * inv * gg[k] + bb[k]);
  ((uint4*)(out + row * DMODEL))[lane] = *(uint4*)o;
}

// -------------------- fused prep + ln1 --------------------
// grid 5201: [0,3072) W transposes, [3072,3152) projb, 3152 mk,
// [3153,5201) ln1 (4 rows/block, per-wave).

__global__ __launch_bounds__(256) void prep_kernel(
    const float* __restrict__ wq, const float* __restrict__ wk,
    const float* __restrict__ wv, const float* __restrict__ wo,
    const float* __restrict__ w1, const float* __restrict__ w2,
    const float* __restrict__ proj,
    unsigned short* __restrict__ wtqkv, unsigned short* __restrict__ wot,
    unsigned short* __restrict__ w1t, unsigned short* __restrict__ w2t,
    unsigned short* __restrict__ pb, unsigned* __restrict__ mk,
    const float* __restrict__ x,
    const float* __restrict__ ln1g, const float* __restrict__ ln1b,
    unsigned short* __restrict__ h_bf) {
  int bid = blockIdx.x;
  if (bid < 3072) {
    const float* src; unsigned short* dst; int R, C, base;
    if (bid < 256)       { src = wq; dst = wtqkv;          R = 512;  C = 512;  base = 0; }
    else if (bid < 512)  { src = wk; dst = wtqkv + 262144; R = 512;  C = 512;  base = 256; }
    else if (bid < 768)  { src = wv; dst = wtqkv + 524288; R = 512;  C = 512;  base = 512; }
    else if (bid < 1024) { src = wo; dst = wot;            R = 512;  C = 512;  base = 768; }
    else if (bid < 2048) { src = w1; dst = w1t;            R = 512;  C = 2048; base = 1024; }
    else                 { src = w2; dst = w2t;            R = 2048; C = 512;  base = 2048; }
    int lb = bid - base;
    int nbx = C / 32;
    int c0 = (lb % nbx) * 32, r0 = (lb / nbx) * 32;
    __shared__ float tile[32][33];
    int tx = threadIdx.x & 31, ty = threadIdx.x >> 5;
    #pragma unroll
    for (int i = ty; i < 32; i += 8)
      tile[i][tx] = src[(long)(r0 + i) * C + c0 + tx];
    __syncthreads();
    #pragma unroll
    for (int i = ty; i < 32; i += 8)
      dst[(long)(c0 + i) * R + r0 + tx] = f2bf(tile[tx][i]);
  } else if (bid < 3152) {
    int id = (bid - 3072) * 256 + threadIdx.x;  // < 320*64
    int j = id >> 6;
    pb[id] = (j < NF) ? f2bf(proj[(long)j * 64 + (id & 63)] * 0.35355339059327373f)
                      : (unsigned short)0;
  } else if (bid == 3152) {
    if (threadIdx.x < NHEAD) mk[threadIdx.x] = 0x007FFFFFu;  // enc(-inf)
  } else {
    long row = (long)(bid - 3153) * 4 + (threadIdx.x >> 6);
    ln_row(x, ln1g, ln1b, h_bf, row, threadIdx.x & 63);
  }
}

// -------------------- layernorm (ln2), 4 rows/block --------------------

__global__ __launch_bounds__(256) void ln_kernel(const float* __restrict__ x,
                                                 const float* __restrict__ g,
                                                 const float* __restrict__ b,
                                                 unsigned short* __restrict__ out) {
  long row = (long)blockIdx.x * 4 + (threadIdx.x >> 6);
  ln_row(x, g, b, out, row, threadIdx.x & 63);
}

enum { EPI_BF16 = 0, EPI_BIAS_RES_F32 = 2, EPI_BIAS_GELU = 3, EPI_QKV = 4 };

// ---------------- gemm8w: 256x64 8-wave counted-vmcnt GEMM (QKV/FFN1) -------

template <int EPI>
__global__ __launch_bounds__(512, 4) void gemm8w_kernel(
    const unsigned short* __restrict__ A, int lda,
    const unsigned short* __restrict__ Bt, int ldb,
    void* __restrict__ Cv, int ldc,
    int K,
    const float* __restrict__ bias,
    const float* __restrict__ res, int ldr,
    unsigned short* __restrict__ vt) {
  constexpr int MR = 4, NR = 2;
  constexpr int S = 5;
  const int tid = threadIdx.x;
  const int wave = tid >> 6, lane = tid & 63;
  const int lr = lane & 15, lg = lane >> 4;
  const int wr = wave >> 1, wc = wave & 1;
  const int m0 = blockIdx.x * 256, n0 = blockIdx.y * 64;

  __shared__ uint4 a_s[2][2048];
  __shared__ uint4 b_s[2][512];

  const unsigned short* asrc[4];
  #pragma unroll
  for (int e = 0; e < 4; ++e) {
    int chunk = e * 512 + tid;
    int r = chunk >> 3, c = chunk & 7;
    asrc[e] = A + (long)(m0 + r) * lda + (c ^ (r & 7)) * 8;
  }
  const unsigned short* bsrc;
  {
    int r = tid >> 3, c = tid & 7;
    bsrc = Bt + (long)(n0 + r) * ldb + (c ^ (r & 7)) * 8;
  }
  const int wbase = tid & 448;

  f32x4 acc[MR][NR] = {};

  auto stage = [&](int buf, int t) {
    #pragma unroll
    for (int e = 0; e < 4; ++e)
      g2l16(asrc[e] + t * 64, &a_s[buf][e * 512 + wbase]);
    g2l16(bsrc + t * 64, &b_s[buf][wbase]);
  };
  auto compute = [&](int buf) {
    #pragma unroll
    for (int ks = 0; ks < 2; ++ks) {
      bf16x8 af[MR], bv[NR];
      #pragma unroll
      for (int i = 0; i < MR; ++i) {
        int r = wr * 64 + i * 16 + lr;
        af[i] = *(const bf16x8*)&a_s[buf][r * 8 + ((ks * 4 + lg) ^ (r & 7))];
      }
      #pragma unroll
      for (int j = 0; j < NR; ++j) {
        int r = wc * 32 + j * 16 + lr;
        bv[j] = *(const bf16x8*)&b_s[buf][r * 8 + ((ks * 4 + lg) ^ (r & 7))];
      }
      #pragma unroll
      for (int i = 0; i < MR; ++i)
        #pragma unroll
        for (int j = 0; j < NR; ++j)
          acc[i][j] = __builtin_amdgcn_mfma_f32_16x16x32_bf16(af[i], bv[j], acc[i][j], 0, 0, 0);
    }
  };

  const int NT = K >> 6;
  stage(0, 0);
  stage(1, 1);
  wait_vmcnt<S>();
  __builtin_amdgcn_s_barrier();

  int cur = 0;
  for (int t = 0; t < NT; ++t) {
    compute(cur);
    if (t + 1 < NT) {
      wait_lgkm0();
      __builtin_amdgcn_s_barrier();
      if (t + 2 < NT) {
        stage(cur, t + 2);
        wait_vmcnt<S>();
      } else {
        wait_vmcnt<0>();
      }
      __builtin_amdgcn_s_barrier();
    }
    cur ^= 1;
  }

  #pragma unroll
  for (int i = 0; i < MR; ++i) {
    #pragma unroll
    for (int j = 0; j < NR; ++j) {
      int gn = n0 + wc * 32 + j * 16 + lr;
      int gm0 = m0 + wr * 64 + i * 16 + lg * 4;
      if (EPI == EPI_QKV && gn >= 1024) {
        int d = gn - 1024;
        uint2 u;
        u.x = (unsigned)f2bf(acc[i][j][0]) | ((unsigned)f2bf(acc[i][j][1]) << 16);
        u.y = (unsigned)f2bf(acc[i][j][2]) | ((unsigned)f2bf(acc[i][j][3]) << 16);
        *(uint2*)(vt + (long)d * N_SEQ + gm0) = u;
        continue;
      }
      #pragma unroll
      for (int rg = 0; rg < 4; ++rg) {
        int gm = gm0 + rg;
        float v = acc[i][j][rg];
        if (EPI == EPI_BF16 || EPI == EPI_QKV) {
          ((unsigned short*)Cv)[(long)gm * ldc + gn] = f2bf(v);
        } else if (EPI == EPI_BIAS_RES_F32) {
          v += bias[gn] + res[(long)gm * ldr + gn];
          ((float*)Cv)[(long)gm * ldc + gn] = v;
        } else if (EPI == EPI_BIAS_GELU) {
          v += bias[gn];
          float t3 = 0.7978845608028654f * (v + 0.044715f * v * v * v);
          v = v / (1.0f + __expf(-2.0f * t3));  // 0.5v(1+tanh(t3))
          ((unsigned short*)Cv)[(long)gm * ldc + gn] = f2bf(v);
        }
      }
    }
  }
}

// -------- counted-vmcnt double-buffered 128x64 4-wave GEMM (WO/FFN2) --------

template <int BM, int BN, int WM, int WN, int EPI>
__global__ __launch_bounds__(256) void gemm_kernel(
    const unsigned short* __restrict__ A, int lda,
    const unsigned short* __restrict__ Bt, int ldb,
    void* __restrict__ Cv, int ldc,
    int K,
    const float* __restrict__ bias,
    const float* __restrict__ res, int ldr) {
  static_assert((BM / WM) * (BN / WN) == 4, "need 4 waves");
  constexpr int MR = WM / 16, NR = WN / 16;
  constexpr int WNN = BN / WN;
  constexpr int AIT = BM * 8 / 256;
  constexpr int BIT = BN * 8 / 256;
  constexpr int S = AIT + BIT;
  static_assert(S == 6, "wait count tuned for BM=128,BN=64");
  const int tid = threadIdx.x;
  const int wave = tid >> 6, lane = tid & 63;
  const int lr = lane & 15, lg = lane >> 4;
  const int wr = wave / WNN, wc = wave % WNN;
  const int m0 = blockIdx.x * BM, n0 = blockIdx.y * BN;

  __shared__ uint4 a_s[2][BM * 8];
  __shared__ uint4 b_s[2][BN * 8];

  const unsigned short* asrc[AIT];
  #pragma unroll
  for (int e = 0; e < AIT; ++e) {
    int chunk = e * 256 + tid;
    int r = chunk >> 3, c = chunk & 7;
    asrc[e] = A + (long)(m0 + r) * lda + (c ^ (r & 7)) * 8;
  }
  const unsigned short* bsrc[BIT];
  #pragma unroll
  for (int e = 0; e < BIT; ++e) {
    int chunk = e * 256 + tid;
    int r = chunk >> 3, c = chunk & 7;
    bsrc[e] = Bt + (long)(n0 + r) * ldb + (c ^ (r & 7)) * 8;
  }
  const int wbase = tid & 192;

  f32x4 acc[MR][NR] = {};

  auto stage = [&](int buf, int t) {
    #pragma unroll
    for (int e = 0; e < AIT; ++e)
      g2l16(asrc[e] + t * 64, &a_s[buf][e * 256 + wbase]);
    #pragma unroll
    for (int e = 0; e < BIT; ++e)
      g2l16(bsrc[e] + t * 64, &b_s[buf][e * 256 + wbase]);
  };
  auto compute = [&](int buf) {
    #pragma unroll
    for (int ks = 0; ks < 2; ++ks) {
      bf16x8 af[MR], bv[NR];
      #pragma unroll
      for (int i = 0; i < MR; ++i) {
        int r = wr * WM + i * 16 + lr;
        af[i] = *(const bf16x8*)&a_s[buf][r * 8 + ((ks * 4 + lg) ^ (r & 7))];
      }
      #pragma unroll
      for (int j = 0; j < NR; ++j) {
        int r = wc * WN + j * 16 + lr;
        bv[j] = *(const bf16x8*)&b_s[buf][r * 8 + ((ks * 4 + lg) ^ (r & 7))];
      }
      #pragma unroll
      for (int i = 0; i < MR; ++i)
        #pragma unroll
        for (int j = 0; j < NR; ++j)
          acc[i][j] = __builtin_amdgcn_mfma_f32_16x16x32_bf16(af[i], bv[j], acc[i][j], 0, 0, 0);
    }
  };

  const int NT = K >> 6;
  stage(0, 0);
  stage(1, 1);
  wait_vmcnt<6>();
  __builtin_amdgcn_s_barrier();

  int cur = 0;
  for (int t = 0; t < NT; ++t) {
    compute(cur);
    if (t + 1 < NT) {
      wait_lgkm0();
      __builtin_amdgcn_s_barrier();
      if (t + 2 < NT) {
        stage(cur, t + 2);
        wait_vmcnt<6>();
      } else {
        wait_vmcnt<0>();
      }
      __builtin_amdgcn_s_barrier();
    }
    cur ^= 1;
  }

  #pragma unroll
  for (int i = 0; i < MR; ++i) {
    #pragma unroll
    for (int j = 0; j < NR; ++j) {
      int gn = n0 + wc * WN + j * 16 + lr;
      #pragma unroll
      for (int rg = 0; rg < 4; ++rg) {
        int gm = m0 + wr * WM + i * 16 + lg * 4 + rg;
        float v = acc[i][j][rg];
        if (EPI == EPI_BF16) {
          ((unsigned short*)Cv)[(long)gm * ldc + gn] = f2bf(v);
        } else if (EPI == EPI_BIAS_RES_F32) {
          v += bias[gn] + res[(long)gm * ldr + gn];
          ((float*)Cv)[(long)gm * ldc + gn] = v;
        } else if (EPI == EPI_BIAS_GELU) {
          v += bias[gn];
          float t3 = 0.7978845608028654f * (v + 0.044715f * v * v * v);
          v = v / (1.0f + __expf(-2.0f * t3));
          ((unsigned short*)Cv)[(long)gm * ldc + gn] = f2bf(v);
        }
      }
    }
  }
}

// ------------- kmax: global max of dd(k) per head, 256 rows/block -----------

__global__ __launch_bounds__(256) void kmax_kernel(
    const unsigned short* __restrict__ Kp,
    const unsigned short* __restrict__ pb,
    unsigned* __restrict__ mk) {
  const int tid = threadIdx.x;
  const int wave = tid >> 6, lane = tid & 63;
  const int lr = lane & 15, lg = lane >> 4;
  const int h = blockIdx.z;
  const int m0 = blockIdx.x * 256;
  const int wbase = tid & 192;

  __shared__ uint4 pbs[2560];
  __shared__ uint4 abuf[2][512];
  __shared__ float sred[4];

  #pragma unroll
  for (int e = 0; e < 10; ++e) {
    int chunk = e * 256 + tid;
    int r = chunk >> 3, c = chunk & 7;
    g2l16(pb + (long)r * DHEAD + (c ^ (r & 7)) * 8, pbs + e * 256 + wbase);
  }
  auto stage_a = [&](int b, int sub) {
    #pragma unroll
    for (int e = 0; e < 2; ++e) {
      int chunk = e * 256 + tid;
      int r = chunk >> 3, c = chunk & 7;
      g2l16(Kp + (long)(m0 + sub * 64 + r) * DQKV + h * DHEAD + (c ^ (r & 7)) * 8,
            abuf[b] + e * 256 + wbase);
    }
  };

  stage_a(0, 0);
  __syncthreads();

  float m = -3.0e38f;
  for (int sub = 0; sub < 4; ++sub) {
    const int cur = sub & 1;
    if (sub + 1 < 4) stage_a(cur ^ 1, sub + 1);

    f32x4 acc[17] = {};
    #pragma unroll
    for (int ks = 0; ks < 2; ++ks) {
      int rA = wave * 16 + lr;
      bf16x8 af = *(const bf16x8*)&abuf[cur][rA * 8 + ((ks * 4 + lg) ^ (rA & 7))];
      #pragma unroll
      for (int j = 0; j < 17; ++j) {
        int rB = j * 16 + lr;
        bf16x8 bv = *(const bf16x8*)&pbs[rB * 8 + ((ks * 4 + lg) ^ (rB & 7))];
        acc[j] = __builtin_amdgcn_mfma_f32_16x16x32_bf16(af, bv, acc[j], 0, 0, 0);
      }
    }
    #pragma unroll
    for (int j = 0; j < 17; ++j) {
      bool valid = (j < 16) || (lr < 10);  // col = j*16+lr < 266
      if (valid) {
        #pragma unroll
        for (int rg = 0; rg < 4; ++rg) m = fmaxf(m, acc[j][rg]);
      }
    }
    if (sub + 1 < 4) __syncthreads();
  }

  #pragma unroll
  for (int s = 1; s < 64; s <<= 1) m = fmaxf(m, __shfl_xor(m, s));
  if (lane == 0) sred[wave] = m;
  __syncthreads();
  if (tid == 0) {
    float mm = fmaxf(fmaxf(sred[0], sred[1]), fmaxf(sred[2], sred[3]));
    atomicMax(&mk[h], enc_f32(mm));
  }
}

// -------------------- ctx_fused: phi(k) + kp^T v + colsums -------------------
// 76KB LDS (pbs 40 + k 8 + v 8 + Pt 20) -> 2 blocks/CU. Single-buffer kv;
// exp/PV done in two 160-feature halves through the 20KB Pt buffer.

__global__ __launch_bounds__(256, 2) void ctx_fused_kernel(
    const unsigned short* __restrict__ Kp,
    const unsigned short* __restrict__ pb,
    const unsigned short* __restrict__ vT,
    const unsigned* __restrict__ mk,
    float* __restrict__ part,
    float* __restrict__ kspart) {
  const int tid = threadIdx.x;
  const int wave = tid >> 6, lane = tid & 63;
  const int lr = lane & 15, lg = lane >> 4;
  const int kc = blockIdx.x, h = blockIdx.y;
  const int wbase = tid & 192;

  __shared__ uint4 smem[4864];
  uint4* pbs  = smem;          // 2560 (40KB)
  uint4* kstg = smem + 2560;   // 512  (8KB)
  uint4* vstg = smem + 3072;   // 512  (8KB)
  uint4* Pt   = smem + 3584;   // 1280 (20KB) — one 160-feature half

  #pragma unroll
  for (int e = 0; e < 10; ++e) {
    int chunk = e * 256 + tid;
    int r = chunk >> 3, c = chunk & 7;
    g2l16(pb + (long)r * DHEAD + (c ^ (r & 7)) * 8, pbs + e * 256 + wbase);
  }

  const float mh = dec_f32(mk[h]);
  f32x4 acc2[2][10] = {};
  float colacc[20];
  #pragma unroll
  for (int j = 0; j < 20; ++j) colacc[j] = 0.f;

  const int wr = wave >> 1, wc = wave & 1;

  for (int sub = 0; sub < 4; ++sub) {
    const int n0 = kc * 256 + sub * 64;
    __syncthreads();  // prev sub's PV reads of vstg / exp region done
    #pragma unroll
    for (int e = 0; e < 2; ++e) {
      int chunk = e * 256 + tid;
      int r = chunk >> 3, c = chunk & 7;
      g2l16(Kp + (long)(n0 + r) * DQKV + h * DHEAD + (c ^ (r & 7)) * 8,
            kstg + e * 256 + wbase);
      g2l16(vT + ((long)h * DHEAD + r) * N_SEQ + n0 + (c ^ (r & 7)) * 8,
            vstg + e * 256 + wbase);
    }
    __syncthreads();  // kv (and pbs on first iter) landed

    // dd GEMM + diag
    f32x4 acc[20] = {};
    float qs = 0.f;
    #pragma unroll
    for (int ks = 0; ks < 2; ++ks) {
      int rA = wave * 16 + lr;
      bf16x8 af = *(const bf16x8*)&kstg[rA * 8 + ((ks * 4 + lg) ^ (rA & 7))];
      #pragma unroll
      for (int i = 0; i < 8; ++i) {
        float f = bf2f((unsigned short)af[i]);
        qs += f * f;
      }
      #pragma unroll
      for (int j = 0; j < 20; ++j) {
        int rB = j * 16 + lr;
        bf16x8 bv = *(const bf16x8*)&pbs[rB * 8 + ((ks * 4 + lg) ^ (rB & 7))];
        acc[j] = __builtin_amdgcn_mfma_f32_16x16x32_bf16(af, bv, acc[j], 0, 0, 0);
      }
    }
    qs += __shfl_xor(qs, 16);
    qs += __shfl_xor(qs, 32);
    float dg[4];
    #pragma unroll
    for (int rg = 0; rg < 4; ++rg) dg[rg] = 0.0625f * __shfl(qs, lg * 4 + rg);

    // two 160-feature halves: exp -> Pt -> PV accumulate
    #pragma unroll
    for (int hf = 0; hf < 2; ++hf) {
      __syncthreads();  // Pt free (prev half's / prev sub's reads done)
      unsigned short* Ptu = (unsigned short*)Pt;
      const int nrow = wave * 16 + lg * 4;
      #pragma unroll
      for (int j = hf * 10; j < hf * 10 + 10; ++j) {
        int colj = j * 16 + lr;
        int rloc = colj - hf * 160;
        #pragma unroll
        for (int rg = 0; rg < 4; ++rg) {
          float v = 0.f;
          if (colj < NF) v = RATIO * (__expf(acc[j][rg] - dg[rg] - mh) + PEPS);
          colacc[j] += v;
          int nr = nrow + rg;
          int idx = ((rloc * 8 + ((nr >> 3) ^ (rloc & 7))) << 3) + (nr & 7);
          Ptu[idx] = f2bf(v);
        }
      }
      __syncthreads();  // Pt half visible

      #pragma unroll
      for (int ks = 0; ks < 2; ++ks) {
        bf16x8 af[2], bv[5];
        #pragma unroll
        for (int i = 0; i < 2; ++i) {
          int r = wr * 32 + i * 16 + lr;
          af[i] = *(const bf16x8*)&vstg[r * 8 + ((ks * 4 + lg) ^ (r & 7))];
        }
        #pragma unroll
        for (int jj = 0; jj < 5; ++jj) {
          int r = wc * 80 + jj * 16 + lr;
          bv[jj] = *(const bf16x8*)&Pt[r * 8 + ((ks * 4 + lg) ^ (r & 7))];
        }
        #pragma unroll
        for (int i = 0; i < 2; ++i)
          #pragma unroll
          for (int jj = 0; jj < 5; ++jj)
            acc2[i][hf * 5 + jj] =
                __builtin_amdgcn_mfma_f32_16x16x32_bf16(af[i], bv[jj], acc2[i][hf * 5 + jj], 0, 0, 0);
      }
    }
  }

  // write ctx partials
  float* pbase = part + ((long)(h * 32 + kc)) * 64 * NFP;
  #pragma unroll
  for (int i = 0; i < 2; ++i) {
    #pragma unroll
    for (int idx = 0; idx < 10; ++idx) {
      int hf = idx / 5, jj = idx % 5;
      int gn = hf * 160 + wc * 80 + jj * 16 + lr;
      #pragma unroll
      for (int rg = 0; rg < 4; ++rg) {
        int gm = wr * 32 + i * 16 + lg * 4 + rg;
        pbase[(long)gm * NFP + gn] = acc2[i][idx][rg];
      }
    }
  }

  __syncthreads();  // all PV reads of Pt done; reuse as float scratch
  float* kls = (float*)Pt;
  #pragma unroll
  for (int j = 0; j < 20; ++j) {
    float cs = colacc[j];
    cs += __shfl_xor(cs, 16);
    cs += __shfl_xor(cs, 32);
    if (lg == 0) kls[wave * NFP + j * 16 + lr] = cs;
  }
  __syncthreads();
  for (int c0 = tid; c0 < NFP; c0 += 256) {
    kspart[((long)(h * 32 + kc)) * NFP + c0] =
        kls[c0] + kls[NFP + c0] + kls[2 * NFP + c0] + kls[3 * NFP + c0];
  }
}

// -------------------- ctxpad build --------------------

__global__ void ctx_reduce_kernel(const float* __restrict__ part,
                                  const float* __restrict__ kspart,
                                  unsigned short* __restrict__ ctxpad) {
  int i = blockIdx.x * 256 + threadIdx.x;  // < 8*96*320 = 245760
  int h = i / (96 * NFP);
  int rem = i % (96 * NFP);
  int r = rem / NFP, j = rem % NFP;
  float s = 0.f;
  if (r < 64) {
    #pragma unroll 4
    for (int kc = 0; kc < 32; ++kc)
      s += part[((long)(h * 32 + kc)) * 64 * NFP + r * NFP + j];
  } else if (r == 64) {
    #pragma unroll 4
    for (int kc = 0; kc < 32; ++kc)
      s += kspart[((long)(h * 32 + kc)) * NFP + j];
  }
  ctxpad[i] = f2bf(s);
}

// -------------------- attn_fused: phi(q) + qp@ctx + dinv --------------------

__global__ __launch_bounds__(256) void attn_fused_kernel(
    const unsigned short* __restrict__ Qp,
    const unsigned short* __restrict__ pb,
    const unsigned short* __restrict__ ctxpad,
    unsigned short* __restrict__ attn) {
  const int tid = threadIdx.x;
  const int wave = tid >> 6, lane = tid & 63;
  const int lr = lane & 15, lg = lane >> 4;
  const int h = blockIdx.z;
  const int m0 = blockIdx.x * 64;
  const int wbase = tid & 192;

  __shared__ uint4 smem[4096];
  auto sbuf = [&](int b) { return smem + b * 768; };
  uint4* Pf = smem + 1536;

  const unsigned short* Aq = Qp + (long)m0 * DQKV + h * DHEAD;
  const unsigned short* Ch = ctxpad + (long)h * 96 * NFP;

  auto stage_ctx = [&](int b, int kk) {
    #pragma unroll
    for (int e = 0; e < 3; ++e) {
      int chunk = e * 256 + tid;
      int r = chunk >> 3, c = chunk & 7;
      g2l16(Ch + (long)r * NFP + kk * 64 + (c ^ (r & 7)) * 8, sbuf(b) + e * 256 + wbase);
    }
  };

  #pragma unroll
  for (int e = 0; e < 2; ++e) {
    int chunk = e * 256 + tid;
    int r = chunk >> 3, c = chunk & 7;
    g2l16(Aq + (long)r * DQKV + (c ^ (r & 7)) * 8, sbuf(0) + e * 256 + wbase);
  }
  #pragma unroll
  for (int e = 0; e < 10; ++e) {
    int chunk = e * 256 + tid;
    int r = chunk >> 3, c = chunk & 7;
    g2l16(pb + (long)r * DHEAD + (c ^ (r & 7)) * 8, Pf + e * 256 + wbase);
  }
  __syncthreads();

  f32x4 acc[20] = {};
  float qs = 0.f;
  #pragma unroll
  for (int ks = 0; ks < 2; ++ks) {
    int rA = wave * 16 + lr;
    bf16x8 af = *(const bf16x8*)&sbuf(0)[rA * 8 + ((ks * 4 + lg) ^ (rA & 7))];
    #pragma unroll
    for (int i = 0; i < 8; ++i) {
      float f = bf2f((unsigned short)af[i]);
      qs += f * f;
    }
    #pragma unroll
    for (int j = 0; j < 20; ++j) {
      int rB = j * 16 + lr;
      bf16x8 bv = *(const bf16x8*)&Pf[rB * 8 + ((ks * 4 + lg) ^ (rB & 7))];
      acc[j] = __builtin_amdgcn_mfma_f32_16x16x32_bf16(af, bv, acc[j], 0, 0, 0);
    }
  }
  qs += __shfl_xor(qs, 16);
  qs += __shfl_xor(qs, 32);
  float dg[4];
  #pragma unroll
  for (int rg = 0; rg < 4; ++rg) dg[rg] = 0.0625f * __shfl(qs, lg * 4 + rg);

  float mrow[4];
  #pragma unroll
  for (int rg = 0; rg < 4; ++rg) mrow[rg] = -3.0e38f;
  #pragma unroll
  for (int j = 0; j < 17; ++j) {
    bool valid = (j < 16) || (lr < 10);
    if (valid) {
      #pragma unroll
      for (int rg = 0; rg < 4; ++rg) mrow[rg] = fmaxf(mrow[rg], acc[j][rg]);
    }
  }
  #pragma unroll
  for (int s = 1; s < 16; s <<= 1)
    #pragma unroll
    for (int rg = 0; rg < 4; ++rg) mrow[rg] = fmaxf(mrow[rg], __shfl_xor(mrow[rg], s));

  __syncthreads();
  stage_ctx(0, 0);

  unsigned short* Pu = (unsigned short*)Pf;
  const int prow = wave * 16 + lg * 4;
  #pragma unroll
  for (int j = 0; j < 20; ++j) {
    int col = j * 16 + lr;
    int kk = col >> 6, cc = (col >> 3) & 7;
    #pragma unroll
    for (int rg = 0; rg < 4; ++rg) {
      float v = 0.f;
      if (col < NF) v = RATIO * (__expf(acc[j][rg] - dg[rg] - mrow[rg]) + PEPS);
      int rw = prow + rg;
      int idx = ((kk * 512 + rw * 8 + (cc ^ (rw & 7))) << 3) + (col & 7);
      Pu[idx] = f2bf(v);
    }
  }
  __syncthreads();

  f32x4 acc2[6] = {};
  #pragma unroll
  for (int kk = 0; kk < 5; ++kk) {
    const int cur = kk & 1;
    if (kk + 1 < 5) stage_ctx(cur ^ 1, kk + 1);
    #pragma unroll
    for (int ks = 0; ks < 2; ++ks) {
      int rA = wave * 16 + lr;
      bf16x8 af = *(const bf16x8*)&Pf[kk * 512 + rA * 8 + ((ks * 4 + lg) ^ (rA & 7))];
      #pragma unroll
      for (int j = 0; j < 6; ++j) {
        int rB = j * 16 + lr;
        bf16x8 bv = *(const bf16x8*)&sbuf(cur)[rB * 8 + ((ks * 4 + lg) ^ (rB & 7))];
        acc2[j] = __builtin_amdgcn_mfma_f32_16x16x32_bf16(af, bv, acc2[j], 0, 0, 0);
      }
    }
    if (kk + 1 < 5) __syncthreads();
  }

  #pragma unroll
  for (int rg = 0; rg < 4; ++rg) {
    float dv = __shfl(acc2[4][rg], lane & 48);
    float inv = 1.0f / dv;
    int gm = m0 + wave * 16 + lg * 4 + rg;
    #pragma unroll
    for (int j = 0; j < 4; ++j) {
      attn[(long)gm * DMODEL + h * DHEAD + j * 16 + lr] = f2bf(acc2[j][rg] * inv);
    }
  }
}

// -------------------- launch --------------------

extern "C" void kernel_launch(void* const* d_in, const int* in_sizes, int n_in,
                              void* d_out, int out_size, void* d_ws, size_t ws_size,
                              hipStream_t stream) {
  const float* x    = (const float*)d_in[0];
  const float* proj = (const float*)d_in[1];
  const float* ln1g = (const float*)d_in[2];
  const float* ln1b = (const float*)d_in[3];
  const float* wq   = (const float*)d_in[4];
  const float* wk   = (const float*)d_in[5];
  const float* wv   = (const float*)d_in[6];
  const float* wo   = (const float*)d_in[7];
  const float* wob  = (const float*)d_in[8];
  const float* ln2g = (const float*)d_in[9];
  const float* ln2b = (const float*)d_in[10];
  const float* w1   = (const float*)d_in[11];
  const float* b1   = (const float*)d_in[12];
  const float* w2   = (const float*)d_in[13];
  const float* b2   = (const float*)d_in[14];

  char* ws = (char*)d_ws;
  unsigned short* wtqkv = (unsigned short*)(ws + 0);
  unsigned short* wot   = (unsigned short*)(ws + 1572864);
  unsigned short* w1t   = (unsigned short*)(ws + 2097152);
  unsigned short* w2t   = (unsigned short*)(ws + 4194304);
  unsigned short* pb    = (unsigned short*)(ws + 6291456);
  unsigned short* h_bf  = (unsigned short*)(ws + 6332416);
  unsigned short* qkv   = (unsigned short*)(ws + 14721024);
  unsigned* mk          = (unsigned*)(ws + 124297216);
  unsigned short* vT    = (unsigned short*)(ws + 124297472);
  float* part           = (float*)(ws + 132686080);
  float* kspart         = (float*)(ws + 153657600);
  unsigned short* ctxpad= (unsigned short*)(ws + 154978560);
  unsigned short* gbf   = (unsigned short*)(ws + 130468096);
  unsigned short* attn  = h_bf;
  unsigned short* h2    = qkv;
  float* xb             = (float*)d_out;

  dim3 blk(256);

  prep_kernel<<<5201, blk, 0, stream>>>(wq, wk, wv, wo, w1, w2, proj,
                                        wtqkv, wot, w1t, w2t, pb, mk,
                                        x, ln1g, ln1b, h_bf);

  // QKV: 256x64, 768 blocks; v column-blocks (by>=16) scatter to vT
  gemm8w_kernel<EPI_QKV><<<dim3(32, 24), dim3(512), 0, stream>>>(
      h_bf, 512, wtqkv, 512, qkv, DQKV, 512, nullptr, nullptr, 0, vT);

  kmax_kernel<<<dim3(32, 1, 8), blk, 0, stream>>>(qkv + 512, pb, mk);

  ctx_fused_kernel<<<dim3(32, 8), blk, 0, stream>>>(qkv + 512, pb, vT, mk, part, kspart);
  ctx_reduce_kernel<<<960, blk, 0, stream>>>(part, kspart, ctxpad);

  attn_fused_kernel<<<dim3(128, 1, 8), blk, 0, stream>>>(qkv, pb, ctxpad, attn);

  // WO: 128x64, 512 blocks
  gemm_kernel<128, 64, 64, 32, EPI_BIAS_RES_F32><<<dim3(64, 8), blk, 0, stream>>>(
      attn, 512, wot, 512, xb, 512, 512, wob, x, 512);

  ln_kernel<<<2048, blk, 0, stream>>>(xb, ln2g, ln2b, h2);

  // FFN1: 256x64, 1024 blocks
  gemm8w_kernel<EPI_BIAS_GELU><<<dim3(32, 32), dim3(512), 0, stream>>>(
      h2, 512, w1t, 512, gbf, 2048, 512, b1, nullptr, 0, nullptr);

  // FFN2: 128x64, 512 blocks (3 blocks/CU — proven best for this shape)
  gemm_kernel<128, 64, 64, 32, EPI_BIAS_RES_F32><<<dim3(64, 8), blk, 0, stream>>>(
      gbf, 2048, w2t, 2048, d_out, 512, 2048, b2, xb, 512);
}

// Round 13
// 163.812 us; speedup vs baseline: 1.1483x; 1.0277x over previous
//
#include <hip/hip_runtime.h>
#include <math.h>

// ---------------------------------------------------------------------------
// Performer encoder layer, MI355X round-13: round-12 traffic cuts with the
// workspace-lifetime bug fixed — xb_bf moved to the free 84MB region at
// 39886848 (was inside gbf's range, so FFN1 clobbered the residual trunk).
// N=8192, D=512, H=8, DH=64, NF=266 (padded to NFP=320 = 5*64).
// Workspace layout (bytes):
//   0         wtqkv  bf16 [1536][512]
//   1572864   wot    bf16 [512][512]
//   2097152   w1t    bf16 [2048][512]
//   4194304   w2t    bf16 [512][2048]
//   6291456   projb  bf16 [320][64]
//   6332416   h_bf   bf16 [8192][512]    (reused as attn)
//   14721024  qkv    bf16 [8192][1536]   (reused as h2)
//   39886848  xb_bf  bf16 [8192][512]    (residual trunk; lives past FFN1)
//   124297216 mk     u32  [8]
//   124297472 vT     bf16 [8][64][8192]
//   132686080 part   bf16 [8][32][64][320]   (dead before FFN1)
//   153657600 kspart f32  [8][32][320]       (dead before FFN1)
//   154978560 ctxpad bf16 [8][96][320]       (dead before FFN1)
//   130468096 gbf    bf16 [8192][2048]       (overlaps part/kspart/ctxpad ONLY)
//   d_out f32 [8192][512] written once by FFN2.
// ---------------------------------------------------------------------------

typedef __attribute__((ext_vector_type(8))) short bf16x8;
typedef __attribute__((ext_vector_type(4))) float f32x4;

#define N_SEQ 8192
#define DMODEL 512
#define DQKV 1536
#define NHEAD 8
#define DHEAD 64
#define NF 266
#define NFP 320
#define PEPS 1e-4f
#define LNEPS 1e-5f
#define RATIO 0.06131393694f

__device__ __forceinline__ unsigned short f2bf(float f) {
  unsigned u = __float_as_uint(f);
  u += 0x7FFFu + ((u >> 16) & 1u);
  return (unsigned short)(u >> 16);
}
__device__ __forceinline__ float bf2f(unsigned short b) {
  return __uint_as_float(((unsigned)b) << 16);
}
__device__ __forceinline__ unsigned enc_f32(float f) {
  unsigned i = __float_as_uint(f);
  return (i & 0x80000000u) ? ~i : (i | 0x80000000u);
}
__device__ __forceinline__ float dec_f32(unsigned u) {
  return (u & 0x80000000u) ? __uint_as_float(u & 0x7FFFFFFFu) : __uint_as_float(~u);
}

__device__ __forceinline__ void g2l16(const void* g, void* l) {
  __builtin_amdgcn_global_load_lds(
      (const __attribute__((address_space(1))) void*)g,
      (__attribute__((address_space(3))) void*)l, 16, 0, 0);
}

template <int N>
__device__ __forceinline__ void wait_vmcnt() {
  if constexpr (N == 0) asm volatile("s_waitcnt vmcnt(0)" ::: "memory");
  else if constexpr (N == 5) asm volatile("s_waitcnt vmcnt(5)" ::: "memory");
  else if constexpr (N == 6) asm volatile("s_waitcnt vmcnt(6)" ::: "memory");
}
__device__ __forceinline__ void wait_lgkm0() {
  asm volatile("s_waitcnt lgkmcnt(0)" ::: "memory");
}

// -------------------- per-wave LayerNorm bodies (1 row / wave) --------------

__device__ __forceinline__ void ln_row(const float* __restrict__ x,
                                       const float* __restrict__ g,
                                       const float* __restrict__ b,
                                       unsigned short* __restrict__ out,
                                       long row, int lane) {
  const float4* xr = (const float4*)(x + row * DMODEL);
  float4 v0 = xr[lane * 2], v1 = xr[lane * 2 + 1];
  float s = v0.x + v0.y + v0.z + v0.w + v1.x + v1.y + v1.z + v1.w;
  #pragma unroll
  for (int m = 32; m >= 1; m >>= 1) s += __shfl_xor(s, m);
  float mu = s * (1.0f / DMODEL);
  float d[8] = {v0.x - mu, v0.y - mu, v0.z - mu, v0.w - mu,
                v1.x - mu, v1.y - mu, v1.z - mu, v1.w - mu};
  float q = 0.f;
  #pragma unroll
  for (int k = 0; k < 8; ++k) q += d[k] * d[k];
  #pragma unroll
  for (int m = 32; m >= 1; m >>= 1) q += __shfl_xor(q, m);
  float inv = rsqrtf(q * (1.0f / DMODEL) + LNEPS);
  const float4* gr = (const float4*)g;
  const float4* br = (const float4*)b;
  float4 g0 = gr[lane * 2], g1 = gr[lane * 2 + 1];
  float4 b0 = br[lane * 2], b1 = br[lane * 2 + 1];
  float gg[8] = {g0.x, g0.y, g0.z, g0.w, g1.x, g1.y, g1.z, g1.w};
  float bb[8] = {b0.x, b0.y, b0.z, b0.w, b1.x, b1.y, b1.z, b1.w};
  unsigned short o[8];
  #pragma unroll
  for (int k = 0; k < 8; ++k) o[k] = f2bf(d[k] * inv * gg[k] + bb[k]);
  ((uint4*)(out + row * DMODEL))[lane] = *(uint4*)o;
}

__device__ __forceinline__ void ln_row_bf(const unsigned short* __restrict__ x,
                                          const float* __restrict__ g,
                                          const float* __restrict__ b,
                                          unsigned short* __restrict__ out,
                                          long row, int lane) {
  uint4 u = ((const uint4*)(x + row * DMODEL))[lane];
  const unsigned short* e = (const unsigned short*)&u;
  float v[8];
  #pragma unroll
  for (int k = 0; k < 8; ++k) v[k] = bf2f(e[k]);
  float s = 0.f;
  #pragma unroll
  for (int k = 0; k < 8; ++k) s += v[k];
  #pragma unroll
  for (int m = 32; m >= 1; m >>= 1) s += __shfl_xor(s, m);
  float mu = s * (1.0f / DMODEL);
  float d[8];
  float q = 0.f;
  #pragma unroll
  for (int k = 0; k < 8; ++k) { d[k] = v[k] - mu; q += d[k] * d[k]; }
  #pragma unroll
  for (int m = 32; m >= 1; m >>= 1) q += __shfl_xor(q, m);
  float inv = rsqrtf(q * (1.0f / DMODEL) + LNEPS);
  const float4* gr = (const float4*)g;
  const float4* br = (const float4*)b;
  float4 g0 = gr[lane * 2], g1 = gr[lane * 2 + 1];
  float4 b0 = br[lane * 2], b1 = br[lane * 2 + 1];
  float gg[8] = {g0.x, g0.y, g0.z, g0.w, g1.x, g1.y, g1.z, g1.w};
  float bb[8] = {b0.x, b0.y, b0.z, b0.w, b1.x, b1.y, b1.z, b1.w};
  unsigned short o[8];
  #pragma unroll
  for (int k = 0; k < 8; ++k) o[k] = f2bf(d[k] * inv * gg[k] + bb[k]);
  ((uint4*)(out + row * DMODEL))[lane] = *(uint4*)o;
}

// -------------------- fused prep + ln1 --------------------

__global__ __launch_bounds__(256) void prep_kernel(
    const float* __restrict__ wq, const float* __restrict__ wk,
    const float* __restrict__ wv, const float* __restrict__ wo,
    const float* __restrict__ w1, const float* __restrict__ w2,
    const float* __restrict__ proj,
    unsigned short* __restrict__ wtqkv, unsigned short* __restrict__ wot,
    unsigned short* __restrict__ w1t, unsigned short* __restrict__ w2t,
    unsigned short* __restrict__ pb, unsigned* __restrict__ mk,
    const float* __restrict__ x,
    const float* __restrict__ ln1g, const float* __restrict__ ln1b,
    unsigned short* __restrict__ h_bf) {
  int bid = blockIdx.x;
  if (bid < 3072) {
    const float* src; unsigned short* dst; int R, C, base;
    if (bid < 256)       { src = wq; dst = wtqkv;          R = 512;  C = 512;  base = 0; }
    else if (bid < 512)  { src = wk; dst = wtqkv + 262144; R = 512;  C = 512;  base = 256; }
    else if (bid < 768)  { src = wv; dst = wtqkv + 524288; R = 512;  C = 512;  base = 512; }
    else if (bid < 1024) { src = wo; dst = wot;            R = 512;  C = 512;  base = 768; }
    else if (bid < 2048) { src = w1; dst = w1t;            R = 512;  C = 2048; base = 1024; }
    else                 { src = w2; dst = w2t;            R = 2048; C = 512;  base = 2048; }
    int lb = bid - base;
    int nbx = C / 32;
    int c0 = (lb % nbx) * 32, r0 = (lb / nbx) * 32;
    __shared__ float tile[32][33];
    int tx = threadIdx.x & 31, ty = threadIdx.x >> 5;
    #pragma unroll
    for (int i = ty; i < 32; i += 8)
      tile[i][tx] = src[(long)(r0 + i) * C + c0 + tx];
    __syncthreads();
    #pragma unroll
    for (int i = ty; i < 32; i += 8)
      dst[(long)(c0 + i) * R + r0 + tx] = f2bf(tile[tx][i]);
  } else if (bid < 3152) {
    int id = (bid - 3072) * 256 + threadIdx.x;  // < 320*64
    int j = id >> 6;
    pb[id] = (j < NF) ? f2bf(proj[(long)j * 64 + (id & 63)] * 0.35355339059327373f)
                      : (unsigned short)0;
  } else if (bid == 3152) {
    if (threadIdx.x < NHEAD) mk[threadIdx.x] = 0x007FFFFFu;  // enc(-inf)
  } else {
    long row = (long)(bid - 3153) * 4 + (threadIdx.x >> 6);
    ln_row(x, ln1g, ln1b, h_bf, row, threadIdx.x & 63);
  }
}

// -------------------- layernorm (ln2), bf16 input, 4 rows/block -------------

__global__ __launch_bounds__(256) void ln_bf_kernel(const unsigned short* __restrict__ x,
                                                    const float* __restrict__ g,
                                                    const float* __restrict__ b,
                                                    unsigned short* __restrict__ out) {
  long row = (long)blockIdx.x * 4 + (threadIdx.x >> 6);
  ln_row_bf(x, g, b, out, row, threadIdx.x & 63);
}

enum { EPI_BF16 = 0, EPI_BIAS_GELU = 3, EPI_QKV = 4, EPI_WO = 5, EPI_FFN2 = 6 };

// ---------------- gemm8w: 256x64 8-wave counted-vmcnt GEMM (QKV/FFN1) -------

template <int EPI>
__global__ __launch_bounds__(512, 4) void gemm8w_kernel(
    const unsigned short* __restrict__ A, int lda,
    const unsigned short* __restrict__ Bt, int ldb,
    void* __restrict__ Cv, int ldc,
    int K,
    const float* __restrict__ bias,
    unsigned short* __restrict__ vt) {
  constexpr int MR = 4, NR = 2;
  constexpr int S = 5;
  const int tid = threadIdx.x;
  const int wave = tid >> 6, lane = tid & 63;
  const int lr = lane & 15, lg = lane >> 4;
  const int wr = wave >> 1, wc = wave & 1;
  const int m0 = blockIdx.x * 256, n0 = blockIdx.y * 64;

  __shared__ uint4 a_s[2][2048];
  __shared__ uint4 b_s[2][512];

  const unsigned short* asrc[4];
  #pragma unroll
  for (int e = 0; e < 4; ++e) {
    int chunk = e * 512 + tid;
    int r = chunk >> 3, c = chunk & 7;
    asrc[e] = A + (long)(m0 + r) * lda + (c ^ (r & 7)) * 8;
  }
  const unsigned short* bsrc;
  {
    int r = tid >> 3, c = tid & 7;
    bsrc = Bt + (long)(n0 + r) * ldb + (c ^ (r & 7)) * 8;
  }
  const int wbase = tid & 448;

  f32x4 acc[MR][NR] = {};

  auto stage = [&](int buf, int t) {
    #pragma unroll
    for (int e = 0; e < 4; ++e)
      g2l16(asrc[e] + t * 64, &a_s[buf][e * 512 + wbase]);
    g2l16(bsrc + t * 64, &b_s[buf][wbase]);
  };
  auto compute = [&](int buf) {
    #pragma unroll
    for (int ks = 0; ks < 2; ++ks) {
      bf16x8 af[MR], bv[NR];
      #pragma unroll
      for (int i = 0; i < MR; ++i) {
        int r = wr * 64 + i * 16 + lr;
        af[i] = *(const bf16x8*)&a_s[buf][r * 8 + ((ks * 4 + lg) ^ (r & 7))];
      }
      #pragma unroll
      for (int j = 0; j < NR; ++j) {
        int r = wc * 32 + j * 16 + lr;
        bv[j] = *(const bf16x8*)&b_s[buf][r * 8 + ((ks * 4 + lg) ^ (r & 7))];
      }
      #pragma unroll
      for (int i = 0; i < MR; ++i)
        #pragma unroll
        for (int j = 0; j < NR; ++j)
          acc[i][j] = __builtin_amdgcn_mfma_f32_16x16x32_bf16(af[i], bv[j], acc[i][j], 0, 0, 0);
    }
  };

  const int NT = K >> 6;
  stage(0, 0);
  stage(1, 1);
  wait_vmcnt<S>();
  __builtin_amdgcn_s_barrier();

  int cur = 0;
  for (int t = 0; t < NT; ++t) {
    compute(cur);
    if (t + 1 < NT) {
      wait_lgkm0();
      __builtin_amdgcn_s_barrier();
      if (t + 2 < NT) {
        stage(cur, t + 2);
        wait_vmcnt<S>();
      } else {
        wait_vmcnt<0>();
      }
      __builtin_amdgcn_s_barrier();
    }
    cur ^= 1;
  }

  #pragma unroll
  for (int i = 0; i < MR; ++i) {
    #pragma unroll
    for (int j = 0; j < NR; ++j) {
      int gn = n0 + wc * 32 + j * 16 + lr;
      int gm0 = m0 + wr * 64 + i * 16 + lg * 4;
      if (EPI == EPI_QKV && gn >= 1024) {
        int d = gn - 1024;
        uint2 u;
        u.x = (unsigned)f2bf(acc[i][j][0]) | ((unsigned)f2bf(acc[i][j][1]) << 16);
        u.y = (unsigned)f2bf(acc[i][j][2]) | ((unsigned)f2bf(acc[i][j][3]) << 16);
        *(uint2*)(vt + (long)d * N_SEQ + gm0) = u;
        continue;
      }
      #pragma unroll
      for (int rg = 0; rg < 4; ++rg) {
        int gm = gm0 + rg;
        float v = acc[i][j][rg];
        if (EPI == EPI_BF16 || EPI == EPI_QKV) {
          ((unsigned short*)Cv)[(long)gm * ldc + gn] = f2bf(v);
        } else if (EPI == EPI_BIAS_GELU) {
          v += bias[gn];
          float t3 = 0.7978845608028654f * (v + 0.044715f * v * v * v);
          v = v / (1.0f + __expf(-2.0f * t3));  // 0.5v(1+tanh(t3))
          ((unsigned short*)Cv)[(long)gm * ldc + gn] = f2bf(v);
        }
      }
    }
  }
}

// -------- counted-vmcnt double-buffered 128x64 4-wave GEMM (WO/FFN2) --------
// EPI_WO:   v += bias + res_f32[gm][gn];  out bf16.
// EPI_FFN2: v += bias + bf2f(res_bf16[gm][gn]); out f32.

template <int BM, int BN, int WM, int WN, int EPI>
__global__ __launch_bounds__(256) void gemm_kernel(
    const unsigned short* __restrict__ A, int lda,
    const unsigned short* __restrict__ Bt, int ldb,
    void* __restrict__ Cv, int ldc,
    int K,
    const float* __restrict__ bias,
    const void* __restrict__ res, int ldr) {
  static_assert((BM / WM) * (BN / WN) == 4, "need 4 waves");
  constexpr int MR = WM / 16, NR = WN / 16;
  constexpr int WNN = BN / WN;
  constexpr int AIT = BM * 8 / 256;
  constexpr int BIT = BN * 8 / 256;
  constexpr int S = AIT + BIT;
  static_assert(S == 6, "wait count tuned for BM=128,BN=64");
  const int tid = threadIdx.x;
  const int wave = tid >> 6, lane = tid & 63;
  const int lr = lane & 15, lg = lane >> 4;
  const int wr = wave / WNN, wc = wave % WNN;
  const int m0 = blockIdx.x * BM, n0 = blockIdx.y * BN;

  __shared__ uint4 a_s[2][BM * 8];
  __shared__ uint4 b_s[2][BN * 8];

  const unsigned short* asrc[AIT];
  #pragma unroll
  for (int e = 0; e < AIT; ++e) {
    int chunk = e * 256 + tid;
    int r = chunk >> 3, c = chunk & 7;
    asrc[e] = A + (long)(m0 + r) * lda + (c ^ (r & 7)) * 8;
  }
  const unsigned short* bsrc[BIT];
  #pragma unroll
  for (int e = 0; e < BIT; ++e) {
    int chunk = e * 256 + tid;
    int r = chunk >> 3, c = chunk & 7;
    bsrc[e] = Bt + (long)(n0 + r) * ldb + (c ^ (r & 7)) * 8;
  }
  const int wbase = tid & 192;

  f32x4 acc[MR][NR] = {};

  auto stage = [&](int buf, int t) {
    #pragma unroll
    for (int e = 0; e < AIT; ++e)
      g2l16(asrc[e] + t * 64, &a_s[buf][e * 256 + wbase]);
    #pragma unroll
    for (int e = 0; e < BIT; ++e)
      g2l16(bsrc[e] + t * 64, &b_s[buf][e * 256 + wbase]);
  };
  auto compute = [&](int buf) {
    #pragma unroll
    for (int ks = 0; ks < 2; ++ks) {
      bf16x8 af[MR], bv[NR];
      #pragma unroll
      for (int i = 0; i < MR; ++i) {
        int r = wr * WM + i * 16 + lr;
        af[i] = *(const bf16x8*)&a_s[buf][r * 8 + ((ks * 4 + lg) ^ (r & 7))];
      }
      #pragma unroll
      for (int j = 0; j < NR; ++j) {
        int r = wc * WN + j * 16 + lr;
        bv[j] = *(const bf16x8*)&b_s[buf][r * 8 + ((ks * 4 + lg) ^ (r & 7))];
      }
      #pragma unroll
      for (int i = 0; i < MR; ++i)
        #pragma unroll
        for (int j = 0; j < NR; ++j)
          acc[i][j] = __builtin_amdgcn_mfma_f32_16x16x32_bf16(af[i], bv[j], acc[i][j], 0, 0, 0);
    }
  };

  const int NT = K >> 6;
  stage(0, 0);
  stage(1, 1);
  wait_vmcnt<6>();
  __builtin_amdgcn_s_barrier();

  int cur = 0;
  for (int t = 0; t < NT; ++t) {
    compute(cur);
    if (t + 1 < NT) {
      wait_lgkm0();
      __builtin_amdgcn_s_barrier();
      if (t + 2 < NT) {
        stage(cur, t + 2);
        wait_vmcnt<6>();
      } else {
        wait_vmcnt<0>();
      }
      __builtin_amdgcn_s_barrier();
    }
    cur ^= 1;
  }

  #pragma unroll
  for (int i = 0; i < MR; ++i) {
    #pragma unroll
    for (int j = 0; j < NR; ++j) {
      int gn = n0 + wc * WN + j * 16 + lr;
      #pragma unroll
      for (int rg = 0; rg < 4; ++rg) {
        int gm = m0 + wr * WM + i * 16 + lg * 4 + rg;
        float v = acc[i][j][rg];
        if (EPI == EPI_WO) {
          v += bias[gn] + ((const float*)res)[(long)gm * ldr + gn];
          ((unsigned short*)Cv)[(long)gm * ldc + gn] = f2bf(v);
        } else if (EPI == EPI_FFN2) {
          v += bias[gn] + bf2f(((const unsigned short*)res)[(long)gm * ldr + gn]);
          ((float*)Cv)[(long)gm * ldc + gn] = v;
        }
      }
    }
  }
}

// ------------- kmax: global max of dd(k) per head, 256 rows/block -----------

__global__ __launch_bounds__(256) void kmax_kernel(
    const unsigned short* __restrict__ Kp,
    const unsigned short* __restrict__ pb,
    unsigned* __restrict__ mk) {
  const int tid = threadIdx.x;
  const int wave = tid >> 6, lane = tid & 63;
  const int lr = lane & 15, lg = lane >> 4;
  const int h = blockIdx.z;
  const int m0 = blockIdx.x * 256;
  const int wbase = tid & 192;

  __shared__ uint4 pbs[2560];
  __shared__ uint4 abuf[2][512];
  __shared__ float sred[4];

  #pragma unroll
  for (int e = 0; e < 10; ++e) {
    int chunk = e * 256 + tid;
    int r = chunk >> 3, c = chunk & 7;
    g2l16(pb + (long)r * DHEAD + (c ^ (r & 7)) * 8, pbs + e * 256 + wbase);
  }
  auto stage_a = [&](int b, int sub) {
    #pragma unroll
    for (int e = 0; e < 2; ++e) {
      int chunk = e * 256 + tid;
      int r = chunk >> 3, c = chunk & 7;
      g2l16(Kp + (long)(m0 + sub * 64 + r) * DQKV + h * DHEAD + (c ^ (r & 7)) * 8,
            abuf[b] + e * 256 + wbase);
    }
  };

  stage_a(0, 0);
  __syncthreads();

  float m = -3.0e38f;
  for (int sub = 0; sub < 4; ++sub) {
    const int cur = sub & 1;
    if (sub + 1 < 4) stage_a(cur ^ 1, sub + 1);

    f32x4 acc[17] = {};
    #pragma unroll
    for (int ks = 0; ks < 2; ++ks) {
      int rA = wave * 16 + lr;
      bf16x8 af = *(const bf16x8*)&abuf[cur][rA * 8 + ((ks * 4 + lg) ^ (rA & 7))];
      #pragma unroll
      for (int j = 0; j < 17; ++j) {
        int rB = j * 16 + lr;
        bf16x8 bv = *(const bf16x8*)&pbs[rB * 8 + ((ks * 4 + lg) ^ (rB & 7))];
        acc[j] = __builtin_amdgcn_mfma_f32_16x16x32_bf16(af, bv, acc[j], 0, 0, 0);
      }
    }
    #pragma unroll
    for (int j = 0; j < 17; ++j) {
      bool valid = (j < 16) || (lr < 10);  // col = j*16+lr < 266
      if (valid) {
        #pragma unroll
        for (int rg = 0; rg < 4; ++rg) m = fmaxf(m, acc[j][rg]);
      }
    }
    if (sub + 1 < 4) __syncthreads();
  }

  #pragma unroll
  for (int s = 1; s < 64; s <<= 1) m = fmaxf(m, __shfl_xor(m, s));
  if (lane == 0) sred[wave] = m;
  __syncthreads();
  if (tid == 0) {
    float mm = fmaxf(fmaxf(sred[0], sred[1]), fmaxf(sred[2], sred[3]));
    atomicMax(&mk[h], enc_f32(mm));
  }
}

// -------------------- ctx_fused: phi(k) + kp^T v + colsums -------------------
// 76KB LDS -> 2 blocks/CU. Partials written bf16.

__global__ __launch_bounds__(256, 2) void ctx_fused_kernel(
    const unsigned short* __restrict__ Kp,
    const unsigned short* __restrict__ pb,
    const unsigned short* __restrict__ vT,
    const unsigned* __restrict__ mk,
    unsigned short* __restrict__ part,   // [8][32][64][320] bf16
    float* __restrict__ kspart) {
  const int tid = threadIdx.x;
  const int wave = tid >> 6, lane = tid & 63;
  const int lr = lane & 15, lg = lane >> 4;
  const int kc = blockIdx.x, h = blockIdx.y;
  const int wbase = tid & 192;

  __shared__ uint4 smem[4864];
  uint4* pbs  = smem;          // 2560 (40KB)
  uint4* kstg = smem + 2560;   // 512  (8KB)
  uint4* vstg = smem + 3072;   // 512  (8KB)
  uint4* Pt   = smem + 3584;   // 1280 (20KB)

  #pragma unroll
  for (int e = 0; e < 10; ++e) {
    int chunk = e * 256 + tid;
    int r = chunk >> 3, c = chunk & 7;
    g2l16(pb + (long)r * DHEAD + (c ^ (r & 7)) * 8, pbs + e * 256 + wbase);
  }

  const float mh = dec_f32(mk[h]);
  f32x4 acc2[2][10] = {};
  float colacc[20];
  #pragma unroll
  for (int j = 0; j < 20; ++j) colacc[j] = 0.f;

  const int wr = wave >> 1, wc = wave & 1;

  for (int sub = 0; sub < 4; ++sub) {
    const int n0 = kc * 256 + sub * 64;
    __syncthreads();
    #pragma unroll
    for (int e = 0; e < 2; ++e) {
      int chunk = e * 256 + tid;
      int r = chunk >> 3, c = chunk & 7;
      g2l16(Kp + (long)(n0 + r) * DQKV + h * DHEAD + (c ^ (r & 7)) * 8,
            kstg + e * 256 + wbase);
      g2l16(vT + ((long)h * DHEAD + r) * N_SEQ + n0 + (c ^ (r & 7)) * 8,
            vstg + e * 256 + wbase);
    }
    __syncthreads();

    f32x4 acc[20] = {};
    float qs = 0.f;
    #pragma unroll
    for (int ks = 0; ks < 2; ++ks) {
      int rA = wave * 16 + lr;
      bf16x8 af = *(const bf16x8*)&kstg[rA * 8 + ((ks * 4 + lg) ^ (rA & 7))];
      #pragma unroll
      for (int i = 0; i < 8; ++i) {
        float f = bf2f((unsigned short)af[i]);
        qs += f * f;
      }
      #pragma unroll
      for (int j = 0; j < 20; ++j) {
        int rB = j * 16 + lr;
        bf16x8 bv = *(const bf16x8*)&pbs[rB * 8 + ((ks * 4 + lg) ^ (rB & 7))];
        acc[j] = __builtin_amdgcn_mfma_f32_16x16x32_bf16(af, bv, acc[j], 0, 0, 0);
      }
    }
    qs += __shfl_xor(qs, 16);
    qs += __shfl_xor(qs, 32);
    float dg[4];
    #pragma unroll
    for (int rg = 0; rg < 4; ++rg) dg[rg] = 0.0625f * __shfl(qs, lg * 4 + rg);

    #pragma unroll
    for (int hf = 0; hf < 2; ++hf) {
      __syncthreads();
      unsigned short* Ptu = (unsigned short*)Pt;
      const int nrow = wave * 16 + lg * 4;
      #pragma unroll
      for (int j = hf * 10; j < hf * 10 + 10; ++j) {
        int colj = j * 16 + lr;
        int rloc = colj - hf * 160;
        #pragma unroll
        for (int rg = 0; rg < 4; ++rg) {
          float v = 0.f;
          if (colj < NF) v = RATIO * (__expf(acc[j][rg] - dg[rg] - mh) + PEPS);
          colacc[j] += v;
          int nr = nrow + rg;
          int idx = ((rloc * 8 + ((nr >> 3) ^ (rloc & 7))) << 3) + (nr & 7);
          Ptu[idx] = f2bf(v);
        }
      }
      __syncthreads();

      #pragma unroll
      for (int ks = 0; ks < 2; ++ks) {
        bf16x8 af[2], bv[5];
        #pragma unroll
        for (int i = 0; i < 2; ++i) {
          int r = wr * 32 + i * 16 + lr;
          af[i] = *(const bf16x8*)&vstg[r * 8 + ((ks * 4 + lg) ^ (r & 7))];
        }
        #pragma unroll
        for (int jj = 0; jj < 5; ++jj) {
          int r = wc * 80 + jj * 16 + lr;
          bv[jj] = *(const bf16x8*)&Pt[r * 8 + ((ks * 4 + lg) ^ (r & 7))];
        }
        #pragma unroll
        for (int i = 0; i < 2; ++i)
          #pragma unroll
          for (int jj = 0; jj < 5; ++jj)
            acc2[i][hf * 5 + jj] =
                __builtin_amdgcn_mfma_f32_16x16x32_bf16(af[i], bv[jj], acc2[i][hf * 5 + jj], 0, 0, 0);
      }
    }
  }

  unsigned short* pbase = part + ((long)(h * 32 + kc)) * 64 * NFP;
  #pragma unroll
  for (int i = 0; i < 2; ++i) {
    #pragma unroll
    for (int idx = 0; idx < 10; ++idx) {
      int hf = idx / 5, jj = idx % 5;
      int gn = hf * 160 + wc * 80 + jj * 16 + lr;
      #pragma unroll
      for (int rg = 0; rg < 4; ++rg) {
        int gm = wr * 32 + i * 16 + lg * 4 + rg;
        pbase[(long)gm * NFP + gn] = f2bf(acc2[i][idx][rg]);
      }
    }
  }

  __syncthreads();
  float* kls = (float*)Pt;
  #pragma unroll
  for (int j = 0; j < 20; ++j) {
    float cs = colacc[j];
    cs += __shfl_xor(cs, 16);
    cs += __shfl_xor(cs, 32);
    if (lg == 0) kls[wave * NFP + j * 16 + lr] = cs;
  }
  __syncthreads();
  for (int c0 = tid; c0 < NFP; c0 += 256) {
    kspart[((long)(h * 32 + kc)) * NFP + c0] =
        kls[c0] + kls[NFP + c0] + kls[2 * NFP + c0] + kls[3 * NFP + c0];
  }
}

// -------------------- ctxpad build --------------------

__global__ void ctx_reduce_kernel(const unsigned short* __restrict__ part,
                                  const float* __restrict__ kspart,
                                  unsigned short* __restrict__ ctxpad) {
  int i = blockIdx.x * 256 + threadIdx.x;  // < 8*96*320 = 245760
  int h = i / (96 * NFP);
  int rem = i % (96 * NFP);
  int r = rem / NFP, j = rem % NFP;
  float s = 0.f;
  if (r < 64) {
    #pragma unroll 4
    for (int kc = 0; kc < 32; ++kc)
      s += bf2f(part[((long)(h * 32 + kc)) * 64 * NFP + r * NFP + j]);
  } else if (r == 64) {
    #pragma unroll 4
    for (int kc = 0; kc < 32; ++kc)
      s += kspart[((long)(h * 32 + kc)) * NFP + j];
  }
  ctxpad[i] = f2bf(s);
}

// -------------------- attn_fused: phi(q) + qp@ctx + dinv --------------------

__global__ __launch_bounds__(256) void attn_fused_kernel(
    const unsigned short* __restrict__ Qp,
    const unsigned short* __restrict__ pb,
    const unsigned short* __restrict__ ctxpad,
    unsigned short* __restrict__ attn) {
  const int tid = threadIdx.x;
  const int wave = tid >> 6, lane = tid & 63;
  const int lr = lane & 15, lg = lane >> 4;
  const int h = blockIdx.z;
  const int m0 = blockIdx.x * 64;
  const int wbase = tid & 192;

  __shared__ uint4 smem[4096];
  auto sbuf = [&](int b) { return smem + b * 768; };
  uint4* Pf = smem + 1536;

  const unsigned short* Aq = Qp + (long)m0 * DQKV + h * DHEAD;
  const unsigned short* Ch = ctxpad + (long)h * 96 * NFP;

  auto stage_ctx = [&](int b, int kk) {
    #pragma unroll
    for (int e = 0; e < 3; ++e) {
      int chunk = e * 256 + tid;
      int r = chunk >> 3, c = chunk & 7;
      g2l16(Ch + (long)r * NFP + kk * 64 + (c ^ (r & 7)) * 8, sbuf(b) + e * 256 + wbase);
    }
  };

  #pragma unroll
  for (int e = 0; e < 2; ++e) {
    int chunk = e * 256 + tid;
    int r = chunk >> 3, c = chunk & 7;
    g2l16(Aq + (long)r * DQKV + (c ^ (r & 7)) * 8, sbuf(0) + e * 256 + wbase);
  }
  #pragma unroll
  for (int e = 0; e < 10; ++e) {
    int chunk = e * 256 + tid;
    int r = chunk >> 3, c = chunk & 7;
    g2l16(pb + (long)r * DHEAD + (c ^ (r & 7)) * 8, Pf + e * 256 + wbase);
  }
  __syncthreads();

  f32x4 acc[20] = {};
  float qs = 0.f;
  #pragma unroll
  for (int ks = 0; ks < 2; ++ks) {
    int rA = wave * 16 + lr;
    bf16x8 af = *(const bf16x8*)&sbuf(0)[rA * 8 + ((ks * 4 + lg) ^ (rA & 7))];
    #pragma unroll
    for (int i = 0; i < 8; ++i) {
      float f = bf2f((unsigned short)af[i]);
      qs += f * f;
    }
    #pragma unroll
    for (int j = 0; j < 20; ++j) {
      int rB = j * 16 + lr;
      bf16x8 bv = *(const bf16x8*)&Pf[rB * 8 + ((ks * 4 + lg) ^ (rB & 7))];
      acc[j] = __builtin_amdgcn_mfma_f32_16x16x32_bf16(af, bv, acc[j], 0, 0, 0);
    }
  }
  qs += __shfl_xor(qs, 16);
  qs += __shfl_xor(qs, 32);
  float dg[4];
  #pragma unroll
  for (int rg = 0; rg < 4; ++rg) dg[rg] = 0.0625f * __shfl(qs, lg * 4 + rg);

  float mrow[4];
  #pragma unroll
  for (int rg = 0; rg < 4; ++rg) mrow[rg] = -3.0e38f;
  #pragma unroll
  for (int j = 0; j < 17; ++j) {
    bool valid = (j < 16) || (lr < 10);
    if (valid) {
      #pragma unroll
      for (int rg = 0; rg < 4; ++rg) mrow[rg] = fmaxf(mrow[rg], acc[j][rg]);
    }
  }
  #pragma unroll
  for (int s = 1; s < 16; s <<= 1)
    #pragma unroll
    for (int rg = 0; rg < 4; ++rg) mrow[rg] = fmaxf(mrow[rg], __shfl_xor(mrow[rg], s));

  __syncthreads();
  stage_ctx(0, 0);

  unsigned short* Pu = (unsigned short*)Pf;
  const int prow = wave * 16 + lg * 4;
  #pragma unroll
  for (int j = 0; j < 20; ++j) {
    int col = j * 16 + lr;
    int kk = col >> 6, cc = (col >> 3) & 7;
    #pragma unroll
    for (int rg = 0; rg < 4; ++rg) {
      float v = 0.f;
      if (col < NF) v = RATIO * (__expf(acc[j][rg] - dg[rg] - mrow[rg]) + PEPS);
      int rw = prow + rg;
      int idx = ((kk * 512 + rw * 8 + (cc ^ (rw & 7))) << 3) + (col & 7);
      Pu[idx] = f2bf(v);
    }
  }
  __syncthreads();

  f32x4 acc2[6] = {};
  #pragma unroll
  for (int kk = 0; kk < 5; ++kk) {
    const int cur = kk & 1;
    if (kk + 1 < 5) stage_ctx(cur ^ 1, kk + 1);
    #pragma unroll
    for (int ks = 0; ks < 2; ++ks) {
      int rA = wave * 16 + lr;
      bf16x8 af = *(const bf16x8*)&Pf[kk * 512 + rA * 8 + ((ks * 4 + lg) ^ (rA & 7))];
      #pragma unroll
      for (int j = 0; j < 6; ++j) {
        int rB = j * 16 + lr;
        bf16x8 bv = *(const bf16x8*)&sbuf(cur)[rB * 8 + ((ks * 4 + lg) ^ (rB & 7))];
        acc2[j] = __builtin_amdgcn_mfma_f32_16x16x32_bf16(af, bv, acc2[j], 0, 0, 0);
      }
    }
    if (kk + 1 < 5) __syncthreads();
  }

  #pragma unroll
  for (int rg = 0; rg < 4; ++rg) {
    float dv = __shfl(acc2[4][rg], lane & 48);
    float inv = 1.0f / dv;
    int gm = m0 + wave * 16 + lg * 4 + rg;
    #pragma unroll
    for (int j = 0; j < 4; ++j) {
      attn[(long)gm * DMODEL + h * DHEAD + j * 16 + lr] = f2bf(acc2[j][rg] * inv);
    }
  }
}

// -------------------- launch --------------------

extern "C" void kernel_launch(void* const* d_in, const int* in_sizes, int n_in,
                              void* d_out, int out_size, void* d_ws, size_t ws_size,
                              hipStream_t stream) {
  const float* x    = (const float*)d_in[0];
  const float* proj = (const float*)d_in[1];
  const float* ln1g = (const float*)d_in[2];
  const float* ln1b = (const float*)d_in[3];
  const float* wq   = (const float*)d_in[4];
  const float* wk   = (const float*)d_in[5];
  const float* wv   = (const float*)d_in[6];
  const float* wo   = (const float*)d_in[7];
  const float* wob  = (const float*)d_in[8];
  const float* ln2g = (const float*)d_in[9];
  const float* ln2b = (const float*)d_in[10];
  const float* w1   = (const float*)d_in[11];
  const float* b1   = (const float*)d_in[12];
  const float* w2   = (const float*)d_in[13];
  const float* b2   = (const float*)d_in[14];

  char* ws = (char*)d_ws;
  unsigned short* wtqkv = (unsigned short*)(ws + 0);
  unsigned short* wot   = (unsigned short*)(ws + 1572864);
  unsigned short* w1t   = (unsigned short*)(ws + 2097152);
  unsigned short* w2t   = (unsigned short*)(ws + 4194304);
  unsigned short* pb    = (unsigned short*)(ws + 6291456);
  unsigned short* h_bf  = (unsigned short*)(ws + 6332416);
  unsigned short* qkv   = (unsigned short*)(ws + 14721024);
  unsigned short* xb_bf = (unsigned short*)(ws + 39886848);   // FIX: free region
  unsigned* mk          = (unsigned*)(ws + 124297216);
  unsigned short* vT    = (unsigned short*)(ws + 124297472);
  unsigned short* part  = (unsigned short*)(ws + 132686080);  // bf16
  float* kspart         = (float*)(ws + 153657600);
  unsigned short* ctxpad= (unsigned short*)(ws + 154978560);
  unsigned short* gbf   = (unsigned short*)(ws + 130468096);
  unsigned short* attn  = h_bf;
  unsigned short* h2    = qkv;

  dim3 blk(256);

  prep_kernel<<<5201, blk, 0, stream>>>(wq, wk, wv, wo, w1, w2, proj,
                                        wtqkv, wot, w1t, w2t, pb, mk,
                                        x, ln1g, ln1b, h_bf);

  // QKV: 256x64, 768 blocks; v column-blocks scatter to vT
  gemm8w_kernel<EPI_QKV><<<dim3(32, 24), dim3(512), 0, stream>>>(
      h_bf, 512, wtqkv, 512, qkv, DQKV, 512, nullptr, vT);

  kmax_kernel<<<dim3(32, 1, 8), blk, 0, stream>>>(qkv + 512, pb, mk);

  ctx_fused_kernel<<<dim3(32, 8), blk, 0, stream>>>(qkv + 512, pb, vT, mk, part, kspart);
  ctx_reduce_kernel<<<960, blk, 0, stream>>>(part, kspart, ctxpad);

  attn_fused_kernel<<<dim3(128, 1, 8), blk, 0, stream>>>(qkv, pb, ctxpad, attn);

  // WO: 128x64, 512 blocks; res = x (f32), out = xb_bf (bf16)
  gemm_kernel<128, 64, 64, 32, EPI_WO><<<dim3(64, 8), blk, 0, stream>>>(
      attn, 512, wot, 512, xb_bf, 512, 512, wob, x, 512);

  ln_bf_kernel<<<2048, blk, 0, stream>>>(xb_bf, ln2g, ln2b, h2);

  // FFN1: 256x64, 1024 blocks
  gemm8w_kernel<EPI_BIAS_GELU><<<dim3(32, 32), dim3(512), 0, stream>>>(
      h2, 512, w1t, 512, gbf, 2048, 512, b1, nullptr);

  // FFN2: 128x64, 512 blocks; res = xb_bf, out = d_out (f32)
  gemm_kernel<128, 64, 64, 32, EPI_FFN2><<<dim3(64, 8), blk, 0, stream>>>(
      gbf, 2048, w2t, 2048, d_out, 512, 2048, b2, xb_bf, 512);
}